// Round 7
// baseline (259.812 us; speedup 1.0000x reference)
//
#include <hip/hip_runtime.h>
#include <math.h>

// RCC criss-cross attention, MFMA-bf16 pipeline. B=8, C=192, CQK=64, H=W=128.
//
//  kwcast : Wq|Wk|Wv fp32 -> Wb bf16 pre-swizzled per-phase LDS image; bias
//  kxt    : x fp32 -> xT bf16, pre-swizzled per-(b,h,phase) LDS image
//  kprojM : pipelined gll GEMM -> Qc,Kc [b][w][h][c], Vn [b][c][h][w]
//  ktrv   : V transpose -> Vc [b][c][w][h]
//  kC     : per (b,w): e_h MFMA (diag) -> Mh,Sh; P -> PV MFMA -> O2 [b][h][w][c]
//  kR     : per (b,h): e_w MFMA -> merged scales; PV; fused final epilogue
//
// kC/kR occupancy design (3 blocks/CU):
//   Q -> registers (wave-private score rows, linear global layout)
//   P (32K) overlays K (16K)  [post-scores barrier separates lifetimes]
//   P + scales are wave-local -> no barrier between stats and PV
//   V in 3 x 16KB chunks, next chunk carried in regs (issue-early/write-late)
// kC LDS 48K, kR 49K -> 3 blocks/CU (was 80K/58K -> 2).

#define B_   8
#define C_   192
#define CQK_ 64
#define H_   128
#define W_   128
#define HW_  (H_*W_)

typedef unsigned short u16;
typedef __attribute__((ext_vector_type(8))) short    s16x8;
typedef __attribute__((ext_vector_type(4))) float    f32x4;
typedef __attribute__((ext_vector_type(2))) unsigned u32x2;
#define MFMA_BF16 __builtin_amdgcn_mfma_f32_16x16x32_bf16

__device__ __forceinline__ u16 f2b(float f) {
    unsigned u = __float_as_uint(f);
    return (u16)((u + 0x7fffu + ((u >> 16) & 1u)) >> 16);   // RNE
}
__device__ __forceinline__ float b2f(u16 v) {
    return __uint_as_float(((unsigned)v) << 16);
}
// raw global->LDS 16B/lane: LDS dest = m0 + lane*16 (wave-uniform m0)
__device__ __forceinline__ void gll16(const u16* gsrc, unsigned lds_byte) {
    asm volatile("s_mov_b32 m0, %1\n\t"
                 "global_load_lds_dwordx4 %0, off"
                 :: "v"(gsrc), "s"(lds_byte) : "memory");
}

// ------------------------------------------------ W -> bf16 pre-swizzled + bias
__global__ __launch_bounds__(256) void kwcast(
    const float* __restrict__ Wq, const float* __restrict__ bq,
    const float* __restrict__ Wk, const float* __restrict__ bk,
    const float* __restrict__ Wv, const float* __restrict__ bv,
    u16* __restrict__ Wb, float* __restrict__ Bb)
{
    const int o = blockIdx.x;                // 320 rows
    const float *row, *bias; int oo;
    if (o < 64)        { row = Wq; bias = bq; oo = o;       }
    else if (o < 128)  { row = Wk; bias = bk; oo = o - 64;  }
    else               { row = Wv; bias = bv; oo = o - 128; }
    const int t = threadIdx.x;
    if (t < C_) {
        const int p = t >> 6, cc = t & 63;
        Wb[p*20480 + o*64 + (((cc >> 3) ^ (o & 7)) << 3) + (cc & 7)]
            = f2b(row[oo*C_ + t]);
    }
    if (t == C_) Bb[o] = bias[oo];
}

// ------------------- x fp32 -> xT bf16 LDS-image [b][h][p][w][chunk^(w&7)][8]
__global__ __launch_bounds__(256) void kxt(
    const float* __restrict__ x, u16* __restrict__ xT)
{
    __shared__ u16 T[24576];                 // 48 KB: [c][16 swz chunks][8]
    const int h = blockIdx.x, b = blockIdx.y;
    const float* xb = x + (size_t)b*C_*HW_ + h*W_;
    const int t = threadIdx.x;
    #pragma unroll
    for (int i = 0; i < 24; ++i) {           // stage + cast
        const int ridx = i*256 + t;
        const int c = ridx >> 5, wq = (ridx & 31) << 2;
        const f32x4 v = *(const f32x4*)(const void*)(xb + (size_t)c*HW_ + wq);
        u32x2 pk;
        pk.x = (unsigned)f2b(v[0]) | ((unsigned)f2b(v[1]) << 16);
        pk.y = (unsigned)f2b(v[2]) | ((unsigned)f2b(v[3]) << 16);
        *(u32x2*)(void*)&T[c*128 + (((wq >> 3) ^ ((c >> 3) & 15)) << 3) + (wq & 7)] = pk;
    }
    __syncthreads();
    u16* dst = xT + (size_t)(b*H_ + h)*24576;
    #pragma unroll
    for (int i = 0; i < 12; ++i) {           // emit transposed image
        const int oidx = i*256 + t;
        const int p = oidx >> 10, w = (oidx >> 3) & 127, cp = oidx & 7;
        s16x8 pk;
        #pragma unroll
        for (int e = 0; e < 8; ++e) {
            const int c = p*64 + ((cp ^ (w & 7)) << 3) + e;
            pk[e] = (short)T[c*128 + ((((w >> 3)) ^ ((c >> 3) & 15)) << 3) + (w & 7)];
        }
        *(s16x8*)(void*)(dst + p*8192 + w*64 + cp*8) = pk;
    }
}

// ---------------------------------------------------- MFMA projection GEMM
__global__ __launch_bounds__(256, 2) void kprojM(
    const u16* __restrict__ xT,
    const u16* __restrict__ Wb, const float* __restrict__ Bb,
    u16* __restrict__ Qc, u16* __restrict__ Kc, u16* __restrict__ Vn)
{
    __shared__ u16 lds[36864];               // 72 KB
    u16* ldsW = lds + 16384;
    u16* ldsV = lds + 8192;
    const int h = blockIdx.x, b = blockIdx.y;
    const int t = threadIdx.x, lane = t & 63, wid = t >> 6;
    const int l15 = lane & 15, q = lane >> 4;

    f32x4 acc[8][5];
    #pragma unroll
    for (int ct = 0; ct < 5; ++ct) {
        const float bv = Bb[(ct*4 + wid)*16 + l15];
        #pragma unroll
        for (int r = 0; r < 8; ++r) acc[r][ct] = (f32x4){bv, bv, bv, bv};
    }

    const u16* xTb = xT + (size_t)(b*H_ + h)*24576;
    const unsigned wofs = __builtin_amdgcn_readfirstlane(32768u + (unsigned)wid*1024u);
    const unsigned aofs = __builtin_amdgcn_readfirstlane((unsigned)wid*1024u);

#define STAGE_W(p) do {                                                   \
    const u16* g = Wb + (p)*20480 + wid*512 + lane*8;                     \
    _Pragma("unroll")                                                     \
    for (int i = 0; i < 10; ++i) gll16(g + i*2048, wofs + i*4096); } while(0)
#define STAGE_A(p, ab) do {                                               \
    const u16* g = xTb + (p)*8192 + wid*512 + lane*8;                     \
    _Pragma("unroll")                                                     \
    for (int i = 0; i < 4; ++i)                                           \
        gll16(g + i*2048, aofs + (ab)*16384u + i*4096); } while(0)
#define MFMA_PHASE(ab) do {                                               \
    const u16* bA = lds + (ab)*8192;                                      \
    __builtin_amdgcn_s_setprio(1);                                        \
    _Pragma("unroll")                                                     \
    for (int ks = 0; ks < 2; ++ks) {                                      \
        s16x8 bf[5];                                                      \
        _Pragma("unroll")                                                 \
        for (int ct = 0; ct < 5; ++ct) {                                  \
            const int o = (ct*4 + wid)*16 + l15;                          \
            bf[ct] = *(const s16x8*)(const void*)                         \
                     &ldsW[o*64 + (((ks*4 + q) ^ (o & 7)) << 3)];         \
        }                                                                 \
        _Pragma("unroll")                                                 \
        for (int r = 0; r < 8; ++r) {                                     \
            const int w = r*16 + l15;                                     \
            const s16x8 af = *(const s16x8*)(const void*)                 \
                     &bA[w*64 + (((ks*4 + q) ^ (w & 7)) << 3)];           \
            _Pragma("unroll")                                             \
            for (int ct = 0; ct < 5; ++ct)                                \
                acc[r][ct] = MFMA_BF16(af, bf[ct], acc[r][ct], 0, 0, 0);  \
        }                                                                 \
    }                                                                     \
    __builtin_amdgcn_s_setprio(0); } while(0)

    STAGE_W(0); STAGE_A(0, 0); STAGE_A(1, 1);            // 18 in flight
    asm volatile("s_waitcnt vmcnt(4)" ::: "memory");     // W0+A0 landed
    __builtin_amdgcn_s_barrier();
    MFMA_PHASE(0);
    asm volatile("s_waitcnt lgkmcnt(0)" ::: "memory");
    __builtin_amdgcn_s_barrier();
    STAGE_W(1); STAGE_A(2, 0);                           // A1 + 14 in flight
    asm volatile("s_waitcnt vmcnt(4)" ::: "memory");     // A1+W1 landed
    __builtin_amdgcn_s_barrier();
    MFMA_PHASE(1);
    asm volatile("s_waitcnt lgkmcnt(0)" ::: "memory");
    __builtin_amdgcn_s_barrier();
    STAGE_W(2);
    asm volatile("s_waitcnt vmcnt(0)" ::: "memory");
    __builtin_amdgcn_s_barrier();
    MFMA_PHASE(0);
    asm volatile("s_waitcnt lgkmcnt(0)" ::: "memory");
    __builtin_amdgcn_s_barrier();

    // ---- epilogue: Q/K direct (32B segments), V via LDS transpose
    {
        const int oc = wid*16 + l15;
        #pragma unroll
        for (int r = 0; r < 8; ++r)
            #pragma unroll
            for (int rg = 0; rg < 4; ++rg) {
                const int w = r*16 + q*4 + rg;
                const size_t base = ((size_t)(b*W_ + w)*H_ + h)*CQK_ + oc;
                Qc[base] = f2b(acc[r][0][rg]);
                Kc[base] = f2b(acc[r][1][rg]);
            }
    }
    #pragma unroll
    for (int ct = 2; ct < 5; ++ct) {
        const int c = (ct - 2)*64 + wid*16 + l15;
        #pragma unroll
        for (int r = 0; r < 8; ++r) {
            const int w0 = r*16 + q*4;
            u32x2 pk;
            pk.x = (unsigned)f2b(acc[r][ct][0]) | ((unsigned)f2b(acc[r][ct][1]) << 16);
            pk.y = (unsigned)f2b(acc[r][ct][2]) | ((unsigned)f2b(acc[r][ct][3]) << 16);
            *(u32x2*)(void*)&ldsV[c*128 + (((w0 >> 3) ^ (c & 7)) << 3) + (w0 & 7)] = pk;
        }
    }
    asm volatile("s_waitcnt lgkmcnt(0)" ::: "memory");
    __builtin_amdgcn_s_barrier();
    #pragma unroll
    for (int i = 0; i < 12; ++i) {
        const int idx = i*256 + t;
        const int c = idx >> 4, j = idx & 15;
        const s16x8 v = *(const s16x8*)(const void*)&ldsV[c*128 + j*8];
        *(s16x8*)(void*)&Vn[(size_t)(b*C_ + c)*HW_ + h*W_ + ((j ^ (c & 7)) << 3)] = v;
    }
#undef STAGE_W
#undef STAGE_A
#undef MFMA_PHASE
}

// ------------------------------------------- V transpose: [c][h][w]->[c][w][h]
__global__ __launch_bounds__(256) void ktrv(
    const u16* __restrict__ Vn, u16* __restrict__ Vc)
{
    __shared__ u16 T[128*128];
    const int c = blockIdx.x, b = blockIdx.y;
    const u16* src = Vn + (size_t)(b*C_ + c)*HW_;
    u16*       dst = Vc + (size_t)(b*C_ + c)*HW_;
    const int t = threadIdx.x;
    for (int idx = t; idx < 128*16; idx += 256) {
        const int hh = idx >> 4, o = idx & 15;
        s16x8 v = *(const s16x8*)(void*)(src + hh*128 + o*8);
        *(s16x8*)(void*)(T + hh*128 + ((o ^ (hh & 7)) << 3)) = v;
    }
    __syncthreads();
    const int w = t & 127, half = t >> 7;
    for (int seg = 0; seg < 8; ++seg) {
        const int h0 = half*64 + seg*8;
        s16x8 pk;
        #pragma unroll
        for (int k = 0; k < 8; ++k) {
            const int hh = h0 + k;
            const int chunk = (w >> 3) ^ (hh & 7);
            pk[k] = (short)T[hh*128 + (chunk << 3) + (w & 7)];
        }
        *(s16x8*)(void*)(dst + w*128 + h0) = pk;
    }
}

// ------------- column attention (per b,w): O2 + Mh,Sh [512 thr, 48KB, 3/CU]
__global__ __launch_bounds__(512, 6) void kC(
    const u16* __restrict__ Qc, const u16* __restrict__ Kc,
    const u16* __restrict__ Vc,
    u16* __restrict__ O2, float* __restrict__ Mh, float* __restrict__ Sh)
{
    extern __shared__ char smem[];
    char* ldsK = smem;                       // 16K staging (dies at P)
    char* ldsP = smem;                       // 32K
    char* ldsV = smem + 32768;               // 16K V chunk
    const int w = blockIdx.x, b = blockIdx.y;
    const int t = threadIdx.x, lane = t & 63, wid = t >> 6;
    const int l15 = lane & 15, q = lane >> 4;
    const int arow = (wid << 4) + l15;

    // ---- Q direct to regs (wave-private score rows; linear global layout)
    const u16* qrow = Qc + ((size_t)(b*W_ + w)*H_ + arow)*CQK_;
    s16x8 qf0 = *(const s16x8*)(const void*)(qrow + q*8);
    s16x8 qf1 = *(const s16x8*)(const void*)(qrow + (4 + q)*8);
    // ---- V chunk1 (c 64..127) into regs
    s16x8 vh[2];
    #pragma unroll
    for (int i = 0; i < 2; ++i) {
        const int idx = i*512 + t;
        const int c = 64 + (idx >> 4), o = idx & 15;
        vh[i] = *(const s16x8*)(const void*)
                (Vc + ((size_t)(b*C_ + c)*W_ + w)*H_ + o*8);
    }
    // ---- K -> LDS, V chunk0 -> LDS
    {
        const u16* ksrc = Kc + (size_t)(b*W_ + w)*H_*CQK_;
        for (int idx = t; idx < 1024; idx += 512) {
            const int r = idx >> 3, o = idx & 7;
            *(s16x8*)(ldsK + r*128 + ((o ^ (r & 7)) << 4)) =
                *(const s16x8*)(const void*)(ksrc + idx*8);
        }
    }
    for (int idx = t; idx < 1024; idx += 512) {
        const int lc = idx >> 4, o = idx & 15;
        *(s16x8*)(ldsV + lc*256 + ((o ^ (lc & 7)) << 4)) =
            *(const s16x8*)(const void*)
            (Vc + ((size_t)(b*C_ + lc)*W_ + w)*H_ + o*8);
    }
    __syncthreads();

    // ---- scores: e_h[h][g]
    f32x4 accS[8];
    #pragma unroll
    for (int i = 0; i < 8; ++i) accS[i] = (f32x4){0.f,0.f,0.f,0.f};
    #pragma unroll
    for (int ks = 0; ks < 2; ++ks) {
        const int ch = ks*4 + q;
        const s16x8 af = ks ? qf1 : qf0;
        #pragma unroll
        for (int gt = 0; gt < 8; ++gt) {
            const int br = (gt << 4) + l15;
            s16x8 bf = *(const s16x8*)(ldsK + br*128 + ((ch ^ (br & 7)) << 4));
            accS[gt] = MFMA_BF16(af, bf, accS[gt], 0, 0, 0);
        }
    }
    __syncthreads();                         // K dead -> P region writable

    // ---- diag mask, stats, P (wave-local rows)
    #pragma unroll
    for (int r = 0; r < 4; ++r) {
        const int hh = (wid << 4) + (q << 2) + r;
        #pragma unroll
        for (int gt = 0; gt < 8; ++gt)
            if ((gt << 4) + l15 == hh) accS[gt][r] = -3.0e38f;
        float m = -3.0e38f;
        #pragma unroll
        for (int gt = 0; gt < 8; ++gt) m = fmaxf(m, accS[gt][r]);
        m = fmaxf(m, __shfl_xor(m, 1)); m = fmaxf(m, __shfl_xor(m, 2));
        m = fmaxf(m, __shfl_xor(m, 4)); m = fmaxf(m, __shfl_xor(m, 8));
        float s = 0.f;
        #pragma unroll
        for (int gt = 0; gt < 8; ++gt) {
            const float e = __expf(accS[gt][r] - m);
            s += e;
            const int g = (gt << 4) + l15;
            *(u16*)(ldsP + hh*256 + (((g >> 3) ^ (hh & 7)) << 4) + (g & 7)*2)
                = f2b(e);
        }
        s += __shfl_xor(s, 1); s += __shfl_xor(s, 2);
        s += __shfl_xor(s, 4); s += __shfl_xor(s, 8);
        if (l15 == 0) {
            Mh[(b*W_ + w)*H_ + hh] = m;
            Sh[(b*W_ + w)*H_ + hh] = s;
        }
    }
    // (no barrier: P wave-local, V0 staged since first barrier)

#define KC_PV(accv) do {                                                  \
    _Pragma("unroll")                                                     \
    for (int ks = 0; ks < 4; ++ks) {                                      \
        const int ch = ks*4 + q;                                          \
        s16x8 afp = *(const s16x8*)(ldsP + arow*256 + ((ch ^ (arow & 7)) << 4)); \
        _Pragma("unroll")                                                 \
        for (int ct = 0; ct < 4; ++ct) {                                  \
            const int vr = (ct << 4) + l15;                               \
            s16x8 bfv = *(const s16x8*)(ldsV + vr*256 + ((ch ^ (vr & 7)) << 4)); \
            accv[ct] = MFMA_BF16(afp, bfv, accv[ct], 0, 0, 0);            \
        }                                                                 \
    } } while(0)
#define KC_O2W(accv, cb) do {                                             \
    _Pragma("unroll")                                                     \
    for (int ct = 0; ct < 4; ++ct) {                                      \
        const int c = (cb) + (ct << 4) + l15;                             \
        _Pragma("unroll")                                                 \
        for (int r = 0; r < 4; ++r) {                                     \
            const int hh = (wid << 4) + (q << 2) + r;                     \
            O2[((size_t)(b*H_ + hh)*W_ + w)*C_ + c] = f2b(accv[ct][r]);   \
        }                                                                 \
    } } while(0)

    f32x4 accO[4];
    #pragma unroll
    for (int i = 0; i < 4; ++i) accO[i] = (f32x4){0.f,0.f,0.f,0.f};
    KC_PV(accO);                             // chunk0 (c 0..63)
    __syncthreads();                         // V0 reads done
    #pragma unroll
    for (int i = 0; i < 2; ++i) {            // dsw V1; reload vh <- V2
        const int idx = i*512 + t;
        const int lc = idx >> 4, o = idx & 15;
        *(s16x8*)(ldsV + lc*256 + ((o ^ (lc & 7)) << 4)) = vh[i];
    }
    #pragma unroll
    for (int i = 0; i < 2; ++i) {
        const int idx = i*512 + t;
        const int c = 128 + (idx >> 4), o = idx & 15;
        vh[i] = *(const s16x8*)(const void*)
                (Vc + ((size_t)(b*C_ + c)*W_ + w)*H_ + o*8);
    }
    __syncthreads();                         // V1 visible
    KC_O2W(accO, 0);
    #pragma unroll
    for (int i = 0; i < 4; ++i) accO[i] = (f32x4){0.f,0.f,0.f,0.f};
    KC_PV(accO);                             // chunk1 (c 64..127)
    __syncthreads();                         // V1 reads done
    #pragma unroll
    for (int i = 0; i < 2; ++i) {            // dsw V2
        const int idx = i*512 + t;
        const int lc = idx >> 4, o = idx & 15;
        *(s16x8*)(ldsV + lc*256 + ((o ^ (lc & 7)) << 4)) = vh[i];
    }
    __syncthreads();                         // V2 visible
    KC_O2W(accO, 64);
    #pragma unroll
    for (int i = 0; i < 4; ++i) accO[i] = (f32x4){0.f,0.f,0.f,0.f};
    KC_PV(accO);                             // chunk2 (c 128..191)
    KC_O2W(accO, 128);
#undef KC_PV
#undef KC_O2W
}

// ---- row attention + fused final (per b,h) [512 thr, 49KB LDS, 3/CU]
__global__ __launch_bounds__(512, 6) void kR(
    const u16* __restrict__ Qc, const u16* __restrict__ Kc,
    const u16* __restrict__ Vn, const u16* __restrict__ O2,
    const float* __restrict__ Mh, const float* __restrict__ Sh,
    const float* __restrict__ x, const float* __restrict__ gamma,
    float* __restrict__ out)
{
    extern __shared__ char smem[];
    char*  ldsK  = smem;                     // 16K staging (dies at P)
    char*  ldsP  = smem;                     // 32K
    char*  ldsV  = smem + 32768;             // 16K V chunk
    float* sScw  = (float*)(smem + 49152);   // 512B
    float* sSch  = (float*)(smem + 49664);   // 512B
    const int h = blockIdx.x, b = blockIdx.y;
    const int t = threadIdx.x, lane = t & 63, wid = t >> 6;
    const int l15 = lane & 15, q = lane >> 4;
    const int arow = (wid << 4) + l15;       // score row / PV row base (w)
    const int wbase = (wid << 4) + (q << 2); // this thread's 4 w's (D rows)
    const float gam = gamma[0];

    // ---- Q direct to regs
    const u16* qrow = Qc + ((size_t)(b*W_ + arow)*H_ + h)*CQK_;
    s16x8 qf0 = *(const s16x8*)(const void*)(qrow + q*8);
    s16x8 qf1 = *(const s16x8*)(const void*)(qrow + (4 + q)*8);
    // ---- V chunk1 (c 64..127) into regs
    s16x8 vh[2];
    #pragma unroll
    for (int i = 0; i < 2; ++i) {
        const int idx = i*512 + t;
        const int c = 64 + (idx >> 4), o = idx & 15;
        vh[i] = *(const s16x8*)(const void*)
                (Vn + (size_t)(b*C_ + c)*HW_ + h*W_ + o*8);
    }
    // ---- K -> LDS (16KB-strided 16B granules), V chunk0 -> LDS
    for (int idx = t; idx < 1024; idx += 512) {
        const int r = idx >> 3, o = idx & 7;
        *(s16x8*)(ldsK + r*128 + ((o ^ (r & 7)) << 4)) =
            *(const s16x8*)(const void*)
            (Kc + ((size_t)(b*W_ + r)*H_ + h)*CQK_ + o*8);
    }
    for (int idx = t; idx < 1024; idx += 512) {
        const int lc = idx >> 4, o = idx & 15;
        *(s16x8*)(ldsV + lc*256 + ((o ^ (lc & 7)) << 4)) =
            *(const s16x8*)(const void*)
            (Vn + (size_t)(b*C_ + lc)*HW_ + h*W_ + o*8);
    }
    __syncthreads();

    // ---- scores: e_w[w][v]
    f32x4 accS[8];
    #pragma unroll
    for (int i = 0; i < 8; ++i) accS[i] = (f32x4){0.f,0.f,0.f,0.f};
    #pragma unroll
    for (int ks = 0; ks < 2; ++ks) {
        const int ch = ks*4 + q;
        const s16x8 af = ks ? qf1 : qf0;
        #pragma unroll
        for (int vt = 0; vt < 8; ++vt) {
            const int br = (vt << 4) + l15;
            s16x8 bf = *(const s16x8*)(ldsK + br*128 + ((ch ^ (br & 7)) << 4));
            accS[vt] = MFMA_BF16(af, bf, accS[vt], 0, 0, 0);
        }
    }
    __syncthreads();                         // K dead -> P region writable

    // ---- stats, P (wave-local), merged scales (l15==0 lanes)
    #pragma unroll
    for (int r = 0; r < 4; ++r) {
        const int ww = (wid << 4) + (q << 2) + r;
        float m = -3.0e38f;
        #pragma unroll
        for (int vt = 0; vt < 8; ++vt) m = fmaxf(m, accS[vt][r]);
        m = fmaxf(m, __shfl_xor(m, 1)); m = fmaxf(m, __shfl_xor(m, 2));
        m = fmaxf(m, __shfl_xor(m, 4)); m = fmaxf(m, __shfl_xor(m, 8));
        float s = 0.f;
        #pragma unroll
        for (int vt = 0; vt < 8; ++vt) {
            const float e = __expf(accS[vt][r] - m);
            s += e;
            const int v = (vt << 4) + l15;
            *(u16*)(ldsP + ww*256 + (((v >> 3) ^ (ww & 7)) << 4) + (v & 7)*2)
                = f2b(e);
        }
        s += __shfl_xor(s, 1); s += __shfl_xor(s, 2);
        s += __shfl_xor(s, 4); s += __shfl_xor(s, 8);
        if (l15 == 0) {                      // merge with column stats
            const float mh  = Mh[(b*W_ + ww)*H_ + h];
            const float shv = Sh[(b*W_ + ww)*H_ + h];
            const float M = fmaxf(mh, m);
            const float S = shv*__expf(mh - M) + s*__expf(m - M);
            sScw[ww] = __expf(m - M) / S;
            sSch[ww] = __expf(mh - M) / S;
        }
    }
    // (no barrier: P + scales wave-local; V0 ready since first barrier)

    const u16* o2p = O2 + (size_t)(b*H_ + h)*W_*C_;
    float scw[4], sch[4];
    #pragma unroll
    for (int r = 0; r < 4; ++r) { scw[r] = sScw[wbase + r]; sch[r] = sSch[wbase + r]; }

#define KR_PV(accv) do {                                                  \
    _Pragma("unroll")                                                     \
    for (int ks = 0; ks < 4; ++ks) {                                      \
        const int ch = ks*4 + q;                                          \
        s16x8 afp = *(const s16x8*)(ldsP + arow*256 + ((ch ^ (arow & 7)) << 4)); \
        _Pragma("unroll")                                                 \
        for (int ct = 0; ct < 4; ++ct) {                                  \
            const int vr = (ct << 4) + l15;                               \
            s16x8 bfv = *(const s16x8*)(ldsV + vr*256 + ((ch ^ (vr & 7)) << 4)); \
            accv[ct] = MFMA_BF16(afp, bfv, accv[ct], 0, 0, 0);            \
        }                                                                 \
    } } while(0)
#define KR_PREF(k, o2k, xk) do {                                          \
    _Pragma("unroll")                                                     \
    for (int ct = 0; ct < 4; ++ct) {                                      \
        const int c = (k)*64 + (ct << 4) + l15;                           \
        _Pragma("unroll")                                                 \
        for (int r = 0; r < 4; ++r)                                       \
            o2k[ct][r] = o2p[(size_t)(wbase + r)*C_ + c];                 \
        xk[ct] = *(const f32x4*)(const void*)                             \
                 (x + (size_t)(b*C_ + c)*HW_ + h*W_ + wbase);             \
    } } while(0)
#define KR_EPI(k, accv, o2k, xk) do {                                     \
    _Pragma("unroll")                                                     \
    for (int ct = 0; ct < 4; ++ct) {                                      \
        const int c = (k)*64 + (ct << 4) + l15;                           \
        f32x4 res;                                                        \
        _Pragma("unroll")                                                 \
        for (int r = 0; r < 4; ++r)                                       \
            res[r] = gam*(accv[ct][r]*scw[r] + b2f(o2k[ct][r])*sch[r]) + xk[ct][r]; \
        *(f32x4*)(void*)(out + (size_t)(b*C_ + c)*HW_ + h*W_ + wbase) = res; \
    } } while(0)

    u16  o2a[4][4]; f32x4 xpa[4];
    KR_PREF(0, o2a, xpa);                    // lands during PV0
    f32x4 accO[4];
    #pragma unroll
    for (int i = 0; i < 4; ++i) accO[i] = (f32x4){0.f,0.f,0.f,0.f};
    KR_PV(accO);                             // chunk0 (c 0..63)
    __syncthreads();                         // V0 reads done
    #pragma unroll
    for (int i = 0; i < 2; ++i) {            // dsw V1; reload vh <- V2
        const int idx = i*512 + t;
        const int lc = idx >> 4, o = idx & 15;
        *(s16x8*)(ldsV + lc*256 + ((o ^ (lc & 7)) << 4)) = vh[i];
    }
    #pragma unroll
    for (int i = 0; i < 2; ++i) {
        const int idx = i*512 + t;
        const int c = 128 + (idx >> 4), o = idx & 15;
        vh[i] = *(const s16x8*)(const void*)
                (Vn + (size_t)(b*C_ + c)*HW_ + h*W_ + o*8);
    }
    u16  o2b[4][4]; f32x4 xpb[4];
    KR_PREF(1, o2b, xpb);
    __syncthreads();                         // V1 visible
    KR_EPI(0, accO, o2a, xpa);
    #pragma unroll
    for (int i = 0; i < 4; ++i) accO[i] = (f32x4){0.f,0.f,0.f,0.f};
    KR_PV(accO);                             // chunk1 (c 64..127)
    __syncthreads();                         // V1 reads done
    #pragma unroll
    for (int i = 0; i < 2; ++i) {            // dsw V2
        const int idx = i*512 + t;
        const int lc = idx >> 4, o = idx & 15;
        *(s16x8*)(ldsV + lc*256 + ((o ^ (lc & 7)) << 4)) = vh[i];
    }
    u16  o2c[4][4]; f32x4 xpc[4];
    KR_PREF(2, o2c, xpc);
    __syncthreads();                         // V2 visible
    KR_EPI(1, accO, o2b, xpb);
    #pragma unroll
    for (int i = 0; i < 4; ++i) accO[i] = (f32x4){0.f,0.f,0.f,0.f};
    KR_PV(accO);                             // chunk2 (c 128..191)
    KR_EPI(2, accO, o2c, xpc);
#undef KR_PV
#undef KR_PREF
#undef KR_EPI
}

extern "C" void kernel_launch(void* const* d_in, const int* in_sizes, int n_in,
                              void* d_out, int out_size, void* d_ws, size_t ws_size,
                              hipStream_t stream)
{
    const float* x  = (const float*)d_in[0];
    const float* Wq = (const float*)d_in[1];
    const float* bq = (const float*)d_in[2];
    const float* Wk = (const float*)d_in[3];
    const float* bk = (const float*)d_in[4];
    const float* Wv = (const float*)d_in[5];
    const float* bv = (const float*)d_in[6];
    const float* gm = (const float*)d_in[7];
    float* out = (float*)d_out;

    u16* Qc = (u16*)d_ws;
    u16* Kc = Qc + 8388608;
    u16* Vn = Kc + 8388608;
    u16* Vc = Vn + 25165824;
    u16* O2 = Vc + 25165824;                 // 25165824 u16
    u16* xT = O2;                            // alias: xT dead before kC writes O2
    float* Mh = (float*)(O2 + 25165824);
    float* Sh = Mh + 131072;
    u16*  Wb = (u16*)(Sh + 131072);          // 61440 u16
    float* Bb = (float*)(Wb + 61440);        // 320 f32

    hipLaunchKernelGGL(kwcast, dim3(320), dim3(256), 0, stream,
                       Wq, bq, Wk, bk, Wv, bv, Wb, Bb);
    hipLaunchKernelGGL(kxt, dim3(H_, B_), dim3(256), 0, stream, x, xT);
    hipLaunchKernelGGL(kprojM, dim3(H_, B_), dim3(256), 0, stream,
                       xT, Wb, Bb, Qc, Kc, Vn);
    hipLaunchKernelGGL(ktrv, dim3(C_, B_), dim3(256), 0, stream, Vn, Vc);
    hipLaunchKernelGGL(kC, dim3(W_, B_), dim3(512), 49152, stream,
                       Qc, Kc, Vc, O2, Mh, Sh);
    hipLaunchKernelGGL(kR, dim3(H_, B_), dim3(512), 50176, stream,
                       Qc, Kc, Vn, O2, Mh, Sh, x, gm, out);
}

// Round 8
// 197.914 us; speedup vs baseline: 1.3128x; 1.3128x over previous
//
#include <hip/hip_runtime.h>
#include <math.h>

// RCC criss-cross attention, MFMA-bf16 pipeline. B=8, C=192, CQK=64, H=W=128.
//
//  kwcast : Wq|Wk|Wv fp32 -> Wb bf16 pre-swizzled per-phase LDS image; bias
//  kxt    : x fp32 -> xT bf16, pre-swizzled per-(b,h,phase) LDS image
//  kprojM : pipelined gll GEMM -> Qc,Kc [b][w][h][c], Vn [b][c][h][w]
//  ktrv   : V transpose -> Vc [b][c][w][h]
//  kC     : per (b,w): e_h MFMA (diag) -> Mh,Sh; P -> PV MFMA -> O2 [b][h][w][c]
//  kR     : per (b,h): e_w MFMA -> merged scales; PV in 3 V-chunks; fused final
//
// kR v3 (lean-register 3 blocks/CU): Q in regs; P(32K) overlays K(16K);
// V cycles through one 16K buffer with a single reg-carried next chunk;
// x/O2 read directly in epilogues (NO multi-phase prefetch arrays - the
// r7 triple-prefetch forced spills under launch_bounds(512,6): VGPR 40 +
// scratch = 448MB HBM. Keep peak live regs ~70 < 85).

#define B_   8
#define C_   192
#define CQK_ 64
#define H_   128
#define W_   128
#define HW_  (H_*W_)

typedef unsigned short u16;
typedef __attribute__((ext_vector_type(8))) short    s16x8;
typedef __attribute__((ext_vector_type(4))) float    f32x4;
typedef __attribute__((ext_vector_type(2))) unsigned u32x2;
#define MFMA_BF16 __builtin_amdgcn_mfma_f32_16x16x32_bf16

__device__ __forceinline__ u16 f2b(float f) {
    unsigned u = __float_as_uint(f);
    return (u16)((u + 0x7fffu + ((u >> 16) & 1u)) >> 16);   // RNE
}
__device__ __forceinline__ float b2f(u16 v) {
    return __uint_as_float(((unsigned)v) << 16);
}
// raw global->LDS 16B/lane: LDS dest = m0 + lane*16 (wave-uniform m0)
__device__ __forceinline__ void gll16(const u16* gsrc, unsigned lds_byte) {
    asm volatile("s_mov_b32 m0, %1\n\t"
                 "global_load_lds_dwordx4 %0, off"
                 :: "v"(gsrc), "s"(lds_byte) : "memory");
}

// ------------------------------------------------ W -> bf16 pre-swizzled + bias
__global__ __launch_bounds__(256) void kwcast(
    const float* __restrict__ Wq, const float* __restrict__ bq,
    const float* __restrict__ Wk, const float* __restrict__ bk,
    const float* __restrict__ Wv, const float* __restrict__ bv,
    u16* __restrict__ Wb, float* __restrict__ Bb)
{
    const int o = blockIdx.x;                // 320 rows
    const float *row, *bias; int oo;
    if (o < 64)        { row = Wq; bias = bq; oo = o;       }
    else if (o < 128)  { row = Wk; bias = bk; oo = o - 64;  }
    else               { row = Wv; bias = bv; oo = o - 128; }
    const int t = threadIdx.x;
    if (t < C_) {
        const int p = t >> 6, cc = t & 63;
        Wb[p*20480 + o*64 + (((cc >> 3) ^ (o & 7)) << 3) + (cc & 7)]
            = f2b(row[oo*C_ + t]);
    }
    if (t == C_) Bb[o] = bias[oo];
}

// ------------------- x fp32 -> xT bf16 LDS-image [b][h][p][w][chunk^(w&7)][8]
__global__ __launch_bounds__(256) void kxt(
    const float* __restrict__ x, u16* __restrict__ xT)
{
    __shared__ u16 T[24576];                 // 48 KB: [c][16 swz chunks][8]
    const int h = blockIdx.x, b = blockIdx.y;
    const float* xb = x + (size_t)b*C_*HW_ + h*W_;
    const int t = threadIdx.x;
    #pragma unroll
    for (int i = 0; i < 24; ++i) {           // stage + cast
        const int ridx = i*256 + t;
        const int c = ridx >> 5, wq = (ridx & 31) << 2;
        const f32x4 v = *(const f32x4*)(const void*)(xb + (size_t)c*HW_ + wq);
        u32x2 pk;
        pk.x = (unsigned)f2b(v[0]) | ((unsigned)f2b(v[1]) << 16);
        pk.y = (unsigned)f2b(v[2]) | ((unsigned)f2b(v[3]) << 16);
        *(u32x2*)(void*)&T[c*128 + (((wq >> 3) ^ ((c >> 3) & 15)) << 3) + (wq & 7)] = pk;
    }
    __syncthreads();
    u16* dst = xT + (size_t)(b*H_ + h)*24576;
    #pragma unroll
    for (int i = 0; i < 12; ++i) {           // emit transposed image
        const int oidx = i*256 + t;
        const int p = oidx >> 10, w = (oidx >> 3) & 127, cp = oidx & 7;
        s16x8 pk;
        #pragma unroll
        for (int e = 0; e < 8; ++e) {
            const int c = p*64 + ((cp ^ (w & 7)) << 3) + e;
            pk[e] = (short)T[c*128 + ((((w >> 3)) ^ ((c >> 3) & 15)) << 3) + (w & 7)];
        }
        *(s16x8*)(void*)(dst + p*8192 + w*64 + cp*8) = pk;
    }
}

// ---------------------------------------------------- MFMA projection GEMM
__global__ __launch_bounds__(256, 2) void kprojM(
    const u16* __restrict__ xT,
    const u16* __restrict__ Wb, const float* __restrict__ Bb,
    u16* __restrict__ Qc, u16* __restrict__ Kc, u16* __restrict__ Vn)
{
    __shared__ u16 lds[36864];               // 72 KB
    u16* ldsW = lds + 16384;
    u16* ldsV = lds + 8192;
    const int h = blockIdx.x, b = blockIdx.y;
    const int t = threadIdx.x, lane = t & 63, wid = t >> 6;
    const int l15 = lane & 15, q = lane >> 4;

    f32x4 acc[8][5];
    #pragma unroll
    for (int ct = 0; ct < 5; ++ct) {
        const float bv = Bb[(ct*4 + wid)*16 + l15];
        #pragma unroll
        for (int r = 0; r < 8; ++r) acc[r][ct] = (f32x4){bv, bv, bv, bv};
    }

    const u16* xTb = xT + (size_t)(b*H_ + h)*24576;
    const unsigned wofs = __builtin_amdgcn_readfirstlane(32768u + (unsigned)wid*1024u);
    const unsigned aofs = __builtin_amdgcn_readfirstlane((unsigned)wid*1024u);

#define STAGE_W(p) do {                                                   \
    const u16* g = Wb + (p)*20480 + wid*512 + lane*8;                     \
    _Pragma("unroll")                                                     \
    for (int i = 0; i < 10; ++i) gll16(g + i*2048, wofs + i*4096); } while(0)
#define STAGE_A(p, ab) do {                                               \
    const u16* g = xTb + (p)*8192 + wid*512 + lane*8;                     \
    _Pragma("unroll")                                                     \
    for (int i = 0; i < 4; ++i)                                           \
        gll16(g + i*2048, aofs + (ab)*16384u + i*4096); } while(0)
#define MFMA_PHASE(ab) do {                                               \
    const u16* bA = lds + (ab)*8192;                                      \
    __builtin_amdgcn_s_setprio(1);                                        \
    _Pragma("unroll")                                                     \
    for (int ks = 0; ks < 2; ++ks) {                                      \
        s16x8 bf[5];                                                      \
        _Pragma("unroll")                                                 \
        for (int ct = 0; ct < 5; ++ct) {                                  \
            const int o = (ct*4 + wid)*16 + l15;                          \
            bf[ct] = *(const s16x8*)(const void*)                         \
                     &ldsW[o*64 + (((ks*4 + q) ^ (o & 7)) << 3)];         \
        }                                                                 \
        _Pragma("unroll")                                                 \
        for (int r = 0; r < 8; ++r) {                                     \
            const int w = r*16 + l15;                                     \
            const s16x8 af = *(const s16x8*)(const void*)                 \
                     &bA[w*64 + (((ks*4 + q) ^ (w & 7)) << 3)];           \
            _Pragma("unroll")                                             \
            for (int ct = 0; ct < 5; ++ct)                                \
                acc[r][ct] = MFMA_BF16(af, bf[ct], acc[r][ct], 0, 0, 0);  \
        }                                                                 \
    }                                                                     \
    __builtin_amdgcn_s_setprio(0); } while(0)

    STAGE_W(0); STAGE_A(0, 0); STAGE_A(1, 1);            // 18 in flight
    asm volatile("s_waitcnt vmcnt(4)" ::: "memory");     // W0+A0 landed
    __builtin_amdgcn_s_barrier();
    MFMA_PHASE(0);
    asm volatile("s_waitcnt lgkmcnt(0)" ::: "memory");
    __builtin_amdgcn_s_barrier();
    STAGE_W(1); STAGE_A(2, 0);                           // A1 + 14 in flight
    asm volatile("s_waitcnt vmcnt(4)" ::: "memory");     // A1+W1 landed
    __builtin_amdgcn_s_barrier();
    MFMA_PHASE(1);
    asm volatile("s_waitcnt lgkmcnt(0)" ::: "memory");
    __builtin_amdgcn_s_barrier();
    STAGE_W(2);
    asm volatile("s_waitcnt vmcnt(0)" ::: "memory");
    __builtin_amdgcn_s_barrier();
    MFMA_PHASE(0);
    asm volatile("s_waitcnt lgkmcnt(0)" ::: "memory");
    __builtin_amdgcn_s_barrier();

    // ---- epilogue: Q/K direct (32B segments), V via LDS transpose
    {
        const int oc = wid*16 + l15;
        #pragma unroll
        for (int r = 0; r < 8; ++r)
            #pragma unroll
            for (int rg = 0; rg < 4; ++rg) {
                const int w = r*16 + q*4 + rg;
                const size_t base = ((size_t)(b*W_ + w)*H_ + h)*CQK_ + oc;
                Qc[base] = f2b(acc[r][0][rg]);
                Kc[base] = f2b(acc[r][1][rg]);
            }
    }
    #pragma unroll
    for (int ct = 2; ct < 5; ++ct) {
        const int c = (ct - 2)*64 + wid*16 + l15;
        #pragma unroll
        for (int r = 0; r < 8; ++r) {
            const int w0 = r*16 + q*4;
            u32x2 pk;
            pk.x = (unsigned)f2b(acc[r][ct][0]) | ((unsigned)f2b(acc[r][ct][1]) << 16);
            pk.y = (unsigned)f2b(acc[r][ct][2]) | ((unsigned)f2b(acc[r][ct][3]) << 16);
            *(u32x2*)(void*)&ldsV[c*128 + (((w0 >> 3) ^ (c & 7)) << 3) + (w0 & 7)] = pk;
        }
    }
    asm volatile("s_waitcnt lgkmcnt(0)" ::: "memory");
    __builtin_amdgcn_s_barrier();
    #pragma unroll
    for (int i = 0; i < 12; ++i) {
        const int idx = i*256 + t;
        const int c = idx >> 4, j = idx & 15;
        const s16x8 v = *(const s16x8*)(const void*)&ldsV[c*128 + j*8];
        *(s16x8*)(void*)&Vn[(size_t)(b*C_ + c)*HW_ + h*W_ + ((j ^ (c & 7)) << 3)] = v;
    }
#undef STAGE_W
#undef STAGE_A
#undef MFMA_PHASE
}

// ------------------------------------------- V transpose: [c][h][w]->[c][w][h]
__global__ __launch_bounds__(256) void ktrv(
    const u16* __restrict__ Vn, u16* __restrict__ Vc)
{
    __shared__ u16 T[128*128];
    const int c = blockIdx.x, b = blockIdx.y;
    const u16* src = Vn + (size_t)(b*C_ + c)*HW_;
    u16*       dst = Vc + (size_t)(b*C_ + c)*HW_;
    const int t = threadIdx.x;
    for (int idx = t; idx < 128*16; idx += 256) {
        const int hh = idx >> 4, o = idx & 15;
        s16x8 v = *(const s16x8*)(void*)(src + hh*128 + o*8);
        *(s16x8*)(void*)(T + hh*128 + ((o ^ (hh & 7)) << 3)) = v;
    }
    __syncthreads();
    const int w = t & 127, half = t >> 7;
    for (int seg = 0; seg < 8; ++seg) {
        const int h0 = half*64 + seg*8;
        s16x8 pk;
        #pragma unroll
        for (int k = 0; k < 8; ++k) {
            const int hh = h0 + k;
            const int chunk = (w >> 3) ^ (hh & 7);
            pk[k] = (short)T[hh*128 + (chunk << 3) + (w & 7)];
        }
        *(s16x8*)(void*)(dst + w*128 + h0) = pk;
    }
}

// ------------- column attention (per b,w): O2 + Mh,Sh [512 thr, 48KB, 3/CU]
__global__ __launch_bounds__(512, 6) void kC(
    const u16* __restrict__ Qc, const u16* __restrict__ Kc,
    const u16* __restrict__ Vc,
    u16* __restrict__ O2, float* __restrict__ Mh, float* __restrict__ Sh)
{
    extern __shared__ char smem[];
    char* ldsK = smem;                       // 16K staging (dies at P)
    char* ldsP = smem;                       // 32K
    char* ldsV = smem + 32768;               // 16K V chunk
    const int w = blockIdx.x, b = blockIdx.y;
    const int t = threadIdx.x, lane = t & 63, wid = t >> 6;
    const int l15 = lane & 15, q = lane >> 4;
    const int arow = (wid << 4) + l15;

    // ---- Q direct to regs (wave-private score rows; linear global layout)
    const u16* qrow = Qc + ((size_t)(b*W_ + w)*H_ + arow)*CQK_;
    s16x8 qf0 = *(const s16x8*)(const void*)(qrow + q*8);
    s16x8 qf1 = *(const s16x8*)(const void*)(qrow + (4 + q)*8);
    // ---- V chunk1 (c 64..127) into regs
    s16x8 vh[2];
    #pragma unroll
    for (int i = 0; i < 2; ++i) {
        const int idx = i*512 + t;
        const int c = 64 + (idx >> 4), o = idx & 15;
        vh[i] = *(const s16x8*)(const void*)
                (Vc + ((size_t)(b*C_ + c)*W_ + w)*H_ + o*8);
    }
    // ---- K -> LDS, V chunk0 -> LDS
    {
        const u16* ksrc = Kc + (size_t)(b*W_ + w)*H_*CQK_;
        for (int idx = t; idx < 1024; idx += 512) {
            const int r = idx >> 3, o = idx & 7;
            *(s16x8*)(ldsK + r*128 + ((o ^ (r & 7)) << 4)) =
                *(const s16x8*)(const void*)(ksrc + idx*8);
        }
    }
    for (int idx = t; idx < 1024; idx += 512) {
        const int lc = idx >> 4, o = idx & 15;
        *(s16x8*)(ldsV + lc*256 + ((o ^ (lc & 7)) << 4)) =
            *(const s16x8*)(const void*)
            (Vc + ((size_t)(b*C_ + lc)*W_ + w)*H_ + o*8);
    }
    __syncthreads();

    // ---- scores: e_h[h][g]
    f32x4 accS[8];
    #pragma unroll
    for (int i = 0; i < 8; ++i) accS[i] = (f32x4){0.f,0.f,0.f,0.f};
    #pragma unroll
    for (int ks = 0; ks < 2; ++ks) {
        const int ch = ks*4 + q;
        const s16x8 af = ks ? qf1 : qf0;
        #pragma unroll
        for (int gt = 0; gt < 8; ++gt) {
            const int br = (gt << 4) + l15;
            s16x8 bf = *(const s16x8*)(ldsK + br*128 + ((ch ^ (br & 7)) << 4));
            accS[gt] = MFMA_BF16(af, bf, accS[gt], 0, 0, 0);
        }
    }
    __syncthreads();                         // K dead -> P region writable

    // ---- diag mask, stats, P (wave-local rows)
    #pragma unroll
    for (int r = 0; r < 4; ++r) {
        const int hh = (wid << 4) + (q << 2) + r;
        #pragma unroll
        for (int gt = 0; gt < 8; ++gt)
            if ((gt << 4) + l15 == hh) accS[gt][r] = -3.0e38f;
        float m = -3.0e38f;
        #pragma unroll
        for (int gt = 0; gt < 8; ++gt) m = fmaxf(m, accS[gt][r]);
        m = fmaxf(m, __shfl_xor(m, 1)); m = fmaxf(m, __shfl_xor(m, 2));
        m = fmaxf(m, __shfl_xor(m, 4)); m = fmaxf(m, __shfl_xor(m, 8));
        float s = 0.f;
        #pragma unroll
        for (int gt = 0; gt < 8; ++gt) {
            const float e = __expf(accS[gt][r] - m);
            s += e;
            const int g = (gt << 4) + l15;
            *(u16*)(ldsP + hh*256 + (((g >> 3) ^ (hh & 7)) << 4) + (g & 7)*2)
                = f2b(e);
        }
        s += __shfl_xor(s, 1); s += __shfl_xor(s, 2);
        s += __shfl_xor(s, 4); s += __shfl_xor(s, 8);
        if (l15 == 0) {
            Mh[(b*W_ + w)*H_ + hh] = m;
            Sh[(b*W_ + w)*H_ + hh] = s;
        }
    }
    // (no barrier: P wave-local, V0 staged since first barrier)

#define KC_PV(accv) do {                                                  \
    _Pragma("unroll")                                                     \
    for (int ks = 0; ks < 4; ++ks) {                                      \
        const int ch = ks*4 + q;                                          \
        s16x8 afp = *(const s16x8*)(ldsP + arow*256 + ((ch ^ (arow & 7)) << 4)); \
        _Pragma("unroll")                                                 \
        for (int ct = 0; ct < 4; ++ct) {                                  \
            const int vr = (ct << 4) + l15;                               \
            s16x8 bfv = *(const s16x8*)(ldsV + vr*256 + ((ch ^ (vr & 7)) << 4)); \
            accv[ct] = MFMA_BF16(afp, bfv, accv[ct], 0, 0, 0);            \
        }                                                                 \
    } } while(0)
#define KC_O2W(accv, cb) do {                                             \
    _Pragma("unroll")                                                     \
    for (int ct = 0; ct < 4; ++ct) {                                      \
        const int c = (cb) + (ct << 4) + l15;                             \
        _Pragma("unroll")                                                 \
        for (int r = 0; r < 4; ++r) {                                     \
            const int hh = (wid << 4) + (q << 2) + r;                     \
            O2[((size_t)(b*H_ + hh)*W_ + w)*C_ + c] = f2b(accv[ct][r]);   \
        }                                                                 \
    } } while(0)

    f32x4 accO[4];
    #pragma unroll
    for (int i = 0; i < 4; ++i) accO[i] = (f32x4){0.f,0.f,0.f,0.f};
    KC_PV(accO);                             // chunk0 (c 0..63)
    __syncthreads();                         // V0 reads done
    #pragma unroll
    for (int i = 0; i < 2; ++i) {            // dsw V1; reload vh <- V2
        const int idx = i*512 + t;
        const int lc = idx >> 4, o = idx & 15;
        *(s16x8*)(ldsV + lc*256 + ((o ^ (lc & 7)) << 4)) = vh[i];
    }
    #pragma unroll
    for (int i = 0; i < 2; ++i) {
        const int idx = i*512 + t;
        const int c = 128 + (idx >> 4), o = idx & 15;
        vh[i] = *(const s16x8*)(const void*)
                (Vc + ((size_t)(b*C_ + c)*W_ + w)*H_ + o*8);
    }
    __syncthreads();                         // V1 visible
    KC_O2W(accO, 0);
    #pragma unroll
    for (int i = 0; i < 4; ++i) accO[i] = (f32x4){0.f,0.f,0.f,0.f};
    KC_PV(accO);                             // chunk1 (c 64..127)
    __syncthreads();                         // V1 reads done
    #pragma unroll
    for (int i = 0; i < 2; ++i) {            // dsw V2
        const int idx = i*512 + t;
        const int lc = idx >> 4, o = idx & 15;
        *(s16x8*)(ldsV + lc*256 + ((o ^ (lc & 7)) << 4)) = vh[i];
    }
    __syncthreads();                         // V2 visible
    KC_O2W(accO, 64);
    #pragma unroll
    for (int i = 0; i < 4; ++i) accO[i] = (f32x4){0.f,0.f,0.f,0.f};
    KC_PV(accO);                             // chunk2 (c 128..191)
    KC_O2W(accO, 128);
#undef KC_PV
#undef KC_O2W
}

// ---- row attention + fused final (per b,h) [512 thr, 49KB LDS, 3/CU, lean]
__global__ __launch_bounds__(512, 6) void kR(
    const u16* __restrict__ Qc, const u16* __restrict__ Kc,
    const u16* __restrict__ Vn, const u16* __restrict__ O2,
    const float* __restrict__ Mh, const float* __restrict__ Sh,
    const float* __restrict__ x, const float* __restrict__ gamma,
    float* __restrict__ out)
{
    extern __shared__ char smem[];
    char*  ldsK  = smem;                     // 16K staging (dies at P)
    char*  ldsP  = smem;                     // 32K
    char*  ldsV  = smem + 32768;             // 16K V chunk
    float* sScw  = (float*)(smem + 49152);   // 512B
    float* sSch  = (float*)(smem + 49664);   // 512B
    const int h = blockIdx.x, b = blockIdx.y;
    const int t = threadIdx.x, lane = t & 63, wid = t >> 6;
    const int l15 = lane & 15, q = lane >> 4;
    const int arow = (wid << 4) + l15;       // score row / P row (w)
    const int wbase = (wid << 4) + (q << 2); // this thread's 4 w's (D rows)
    const float gam = gamma[0];

    // ---- Q direct to regs
    const u16* qrow = Qc + ((size_t)(b*W_ + arow)*H_ + h)*CQK_;
    s16x8 qf0 = *(const s16x8*)(const void*)(qrow + q*8);
    s16x8 qf1 = *(const s16x8*)(const void*)(qrow + (4 + q)*8);
    // ---- V chunk1 (c 64..127) into regs (the ONLY reg-carried prefetch)
    s16x8 vh[2];
    #pragma unroll
    for (int i = 0; i < 2; ++i) {
        const int idx = i*512 + t;
        const int c = 64 + (idx >> 4), o = idx & 15;
        vh[i] = *(const s16x8*)(const void*)
                (Vn + (size_t)(b*C_ + c)*HW_ + h*W_ + o*8);
    }
    // ---- K -> LDS, V chunk0 -> LDS
    for (int idx = t; idx < 1024; idx += 512) {
        const int r = idx >> 3, o = idx & 7;
        *(s16x8*)(ldsK + r*128 + ((o ^ (r & 7)) << 4)) =
            *(const s16x8*)(const void*)
            (Kc + ((size_t)(b*W_ + r)*H_ + h)*CQK_ + o*8);
    }
    for (int idx = t; idx < 1024; idx += 512) {
        const int lc = idx >> 4, o = idx & 15;
        *(s16x8*)(ldsV + lc*256 + ((o ^ (lc & 7)) << 4)) =
            *(const s16x8*)(const void*)
            (Vn + (size_t)(b*C_ + lc)*HW_ + h*W_ + o*8);
    }
    __syncthreads();

    // ---- scores: e_w[w][v]
    f32x4 accS[8];
    #pragma unroll
    for (int i = 0; i < 8; ++i) accS[i] = (f32x4){0.f,0.f,0.f,0.f};
    #pragma unroll
    for (int ks = 0; ks < 2; ++ks) {
        const int ch = ks*4 + q;
        const s16x8 af = ks ? qf1 : qf0;
        #pragma unroll
        for (int vt = 0; vt < 8; ++vt) {
            const int br = (vt << 4) + l15;
            s16x8 bf = *(const s16x8*)(ldsK + br*128 + ((ch ^ (br & 7)) << 4));
            accS[vt] = MFMA_BF16(af, bf, accS[vt], 0, 0, 0);
        }
    }
    __syncthreads();                         // K dead -> P region writable

    // ---- stats, P (wave-local), merged scales (l15==0 lanes, wave-local)
    #pragma unroll
    for (int r = 0; r < 4; ++r) {
        const int ww = (wid << 4) + (q << 2) + r;
        float m = -3.0e38f;
        #pragma unroll
        for (int vt = 0; vt < 8; ++vt) m = fmaxf(m, accS[vt][r]);
        m = fmaxf(m, __shfl_xor(m, 1)); m = fmaxf(m, __shfl_xor(m, 2));
        m = fmaxf(m, __shfl_xor(m, 4)); m = fmaxf(m, __shfl_xor(m, 8));
        float s = 0.f;
        #pragma unroll
        for (int vt = 0; vt < 8; ++vt) {
            const float e = __expf(accS[vt][r] - m);
            s += e;
            const int v = (vt << 4) + l15;
            *(u16*)(ldsP + ww*256 + (((v >> 3) ^ (ww & 7)) << 4) + (v & 7)*2)
                = f2b(e);
        }
        s += __shfl_xor(s, 1); s += __shfl_xor(s, 2);
        s += __shfl_xor(s, 4); s += __shfl_xor(s, 8);
        if (l15 == 0) {                      // merge with column stats
            const float mh  = Mh[(b*W_ + ww)*H_ + h];
            const float shv = Sh[(b*W_ + ww)*H_ + h];
            const float M = fmaxf(mh, m);
            const float S = shv*__expf(mh - M) + s*__expf(m - M);
            sScw[ww] = __expf(m - M) / S;
            sSch[ww] = __expf(mh - M) / S;
        }
    }
    // (no barrier: P + scales wave-local; V0 ready since first barrier)
    float scw[4], sch[4];
    #pragma unroll
    for (int r = 0; r < 4; ++r) { scw[r] = sScw[wbase + r]; sch[r] = sSch[wbase + r]; }

    const u16* o2p = O2 + (size_t)(b*H_ + h)*W_*C_;

#define KR_PV(accv) do {                                                  \
    _Pragma("unroll")                                                     \
    for (int ks = 0; ks < 4; ++ks) {                                      \
        const int ch = ks*4 + q;                                          \
        s16x8 afp = *(const s16x8*)(ldsP + arow*256 + ((ch ^ (arow & 7)) << 4)); \
        _Pragma("unroll")                                                 \
        for (int ct = 0; ct < 4; ++ct) {                                  \
            const int vr = (ct << 4) + l15;                               \
            s16x8 bfv = *(const s16x8*)(ldsV + vr*256 + ((ch ^ (vr & 7)) << 4)); \
            accv[ct] = MFMA_BF16(afp, bfv, accv[ct], 0, 0, 0);            \
        }                                                                 \
    } } while(0)
// direct-read epilogue: no persistent prefetch arrays (VGPR discipline)
#define KR_EPI(k, accv) do {                                              \
    _Pragma("unroll")                                                     \
    for (int ct = 0; ct < 4; ++ct) {                                      \
        const int c = (k)*64 + (ct << 4) + l15;                           \
        const size_t ga = (size_t)(b*C_ + c)*HW_ + h*W_ + wbase;          \
        const f32x4 xv = *(const f32x4*)(const void*)(x + ga);            \
        f32x4 res;                                                        \
        _Pragma("unroll")                                                 \
        for (int r = 0; r < 4; ++r) {                                     \
            const float o2 = b2f(o2p[(size_t)(wbase + r)*C_ + c]);        \
            res[r] = gam*(accv[ct][r]*scw[r] + o2*sch[r]) + xv[r];        \
        }                                                                 \
        *(f32x4*)(void*)(out + ga) = res;                                 \
    } } while(0)

    f32x4 accO[4];
    #pragma unroll
    for (int i = 0; i < 4; ++i) accO[i] = (f32x4){0.f,0.f,0.f,0.f};
    KR_PV(accO);                             // chunk0 (c 0..63)
    __syncthreads();                         // V0 reads done
    #pragma unroll
    for (int i = 0; i < 2; ++i) {            // dsw V1; reload vh <- V2
        const int idx = i*512 + t;
        const int lc = idx >> 4, o = idx & 15;
        *(s16x8*)(ldsV + lc*256 + ((o ^ (lc & 7)) << 4)) = vh[i];
    }
    #pragma unroll
    for (int i = 0; i < 2; ++i) {
        const int idx = i*512 + t;
        const int c = 128 + (idx >> 4), o = idx & 15;
        vh[i] = *(const s16x8*)(const void*)
                (Vn + (size_t)(b*C_ + c)*HW_ + h*W_ + o*8);
    }
    KR_EPI(0, accO);                         // stores cover dsw drain
    __syncthreads();                         // V1 visible
    #pragma unroll
    for (int i = 0; i < 4; ++i) accO[i] = (f32x4){0.f,0.f,0.f,0.f};
    KR_PV(accO);                             // chunk1 (c 64..127)
    __syncthreads();                         // V1 reads done
    #pragma unroll
    for (int i = 0; i < 2; ++i) {            // dsw V2
        const int idx = i*512 + t;
        const int lc = idx >> 4, o = idx & 15;
        *(s16x8*)(ldsV + lc*256 + ((o ^ (lc & 7)) << 4)) = vh[i];
    }
    KR_EPI(1, accO);
    __syncthreads();                         // V2 visible
    #pragma unroll
    for (int i = 0; i < 4; ++i) accO[i] = (f32x4){0.f,0.f,0.f,0.f};
    KR_PV(accO);                             // chunk2 (c 128..191)
    KR_EPI(2, accO);
#undef KR_PV
#undef KR_EPI
}

extern "C" void kernel_launch(void* const* d_in, const int* in_sizes, int n_in,
                              void* d_out, int out_size, void* d_ws, size_t ws_size,
                              hipStream_t stream)
{
    const float* x  = (const float*)d_in[0];
    const float* Wq = (const float*)d_in[1];
    const float* bq = (const float*)d_in[2];
    const float* Wk = (const float*)d_in[3];
    const float* bk = (const float*)d_in[4];
    const float* Wv = (const float*)d_in[5];
    const float* bv = (const float*)d_in[6];
    const float* gm = (const float*)d_in[7];
    float* out = (float*)d_out;

    u16* Qc = (u16*)d_ws;
    u16* Kc = Qc + 8388608;
    u16* Vn = Kc + 8388608;
    u16* Vc = Vn + 25165824;
    u16* O2 = Vc + 25165824;                 // 25165824 u16
    u16* xT = O2;                            // alias: xT dead before kC writes O2
    float* Mh = (float*)(O2 + 25165824);
    float* Sh = Mh + 131072;
    u16*  Wb = (u16*)(Sh + 131072);          // 61440 u16
    float* Bb = (float*)(Wb + 61440);        // 320 f32

    hipLaunchKernelGGL(kwcast, dim3(320), dim3(256), 0, stream,
                       Wq, bq, Wk, bk, Wv, bv, Wb, Bb);
    hipLaunchKernelGGL(kxt, dim3(H_, B_), dim3(256), 0, stream, x, xT);
    hipLaunchKernelGGL(kprojM, dim3(H_, B_), dim3(256), 0, stream,
                       xT, Wb, Bb, Qc, Kc, Vn);
    hipLaunchKernelGGL(ktrv, dim3(C_, B_), dim3(256), 0, stream, Vn, Vc);
    hipLaunchKernelGGL(kC, dim3(W_, B_), dim3(512), 49152, stream,
                       Qc, Kc, Vc, O2, Mh, Sh);
    hipLaunchKernelGGL(kR, dim3(H_, B_), dim3(512), 50176, stream,
                       Qc, Kc, Vn, O2, Mh, Sh, x, gm, out);
}

// Round 9
// 189.460 us; speedup vs baseline: 1.3713x; 1.0446x over previous
//
#include <hip/hip_runtime.h>
#include <math.h>

// RCC criss-cross attention, MFMA-bf16 pipeline. B=8, C=192, CQK=64, H=W=128.
//
//  kwcast : Wq|Wk|Wv fp32 -> Wb bf16 pre-swizzled per-phase LDS image; bias
//  kprojM : fused GEMM, reads x fp32 directly (kxt eliminated):
//           A reg-staged (scalar-pair loads + swizzled u32 ds_writes),
//           W via gll16, counted vmcnt, raw barriers, setprio.
//           -> Qc,Kc [b][w][h][c], Vn [b][c][h][w]
//  ktrv   : V transpose -> Vc [b][c][w][h]
//  kC     : per (b,w): e_h MFMA (diag) -> Mh,Sh; P -> PV MFMA -> O2 [b][h][w][c]
//  kR     : per (b,h): e_w MFMA -> merged scales; PV in 3 V-chunks; fused final
//
// REGISTER DISCIPLINE (r7/r8 lesson): launch_bounds(512,6) -> allocator caps
// ~40 arch VGPRs -> scratch spills (+26..200MB HBM). Use (512,4) everywhere
// on 512-thread kernels. kprojM stays (256,2) (budget 256; acc 160 + stage 32).

#define B_   8
#define C_   192
#define CQK_ 64
#define H_   128
#define W_   128
#define HW_  (H_*W_)

typedef unsigned short u16;
typedef __attribute__((ext_vector_type(8))) short    s16x8;
typedef __attribute__((ext_vector_type(4))) float    f32x4;
typedef __attribute__((ext_vector_type(2))) unsigned u32x2;
#define MFMA_BF16 __builtin_amdgcn_mfma_f32_16x16x32_bf16

__device__ __forceinline__ u16 f2b(float f) {
    unsigned u = __float_as_uint(f);
    return (u16)((u + 0x7fffu + ((u >> 16) & 1u)) >> 16);   // RNE
}
__device__ __forceinline__ float b2f(u16 v) {
    return __uint_as_float(((unsigned)v) << 16);
}
// raw global->LDS 16B/lane: LDS dest = m0 + lane*16 (wave-uniform m0)
__device__ __forceinline__ void gll16(const u16* gsrc, unsigned lds_byte) {
    asm volatile("s_mov_b32 m0, %1\n\t"
                 "global_load_lds_dwordx4 %0, off"
                 :: "v"(gsrc), "s"(lds_byte) : "memory");
}

// ------------------------------------------------ W -> bf16 pre-swizzled + bias
__global__ __launch_bounds__(256) void kwcast(
    const float* __restrict__ Wq, const float* __restrict__ bq,
    const float* __restrict__ Wk, const float* __restrict__ bk,
    const float* __restrict__ Wv, const float* __restrict__ bv,
    u16* __restrict__ Wb, float* __restrict__ Bb)
{
    const int o = blockIdx.x;                // 320 rows
    const float *row, *bias; int oo;
    if (o < 64)        { row = Wq; bias = bq; oo = o;       }
    else if (o < 128)  { row = Wk; bias = bk; oo = o - 64;  }
    else               { row = Wv; bias = bv; oo = o - 128; }
    const int t = threadIdx.x;
    if (t < C_) {
        const int p = t >> 6, cc = t & 63;
        Wb[p*20480 + o*64 + (((cc >> 3) ^ (o & 7)) << 3) + (cc & 7)]
            = f2b(row[oo*C_ + t]);
    }
    if (t == C_) Bb[o] = bias[oo];
}

// ------------------- fused MFMA projection GEMM (reads x fp32 directly)
// LDS u16 idx: ldsA [0,8192) = A tile [w][c-chunk swz]; ldsW [8192,28672).
// Epilogue reuses [0,24576) as V transpose buffer.
__global__ __launch_bounds__(256, 2) void kprojM(
    const float* __restrict__ x,
    const u16* __restrict__ Wb, const float* __restrict__ Bb,
    u16* __restrict__ Qc, u16* __restrict__ Kc, u16* __restrict__ Vn)
{
    __shared__ u16 lds[28672];               // 56 KB
    u16* ldsA = lds;
    u16* ldsW = lds + 8192;
    const int h = blockIdx.x, b = blockIdx.y;
    const int t = threadIdx.x, lane = t & 63, wid = t >> 6;
    const int l15 = lane & 15, q = lane >> 4;
    const float* xb = x + (size_t)b*C_*HW_ + h*W_;
    const int wql = t & 127, cpair = (t >> 7) << 1;

    f32x4 acc[8][5];
    #pragma unroll
    for (int ct = 0; ct < 5; ++ct) {
        const float bv = Bb[(ct*4 + wid)*16 + l15];
        #pragma unroll
        for (int r = 0; r < 8; ++r) acc[r][ct] = (f32x4){bv, bv, bv, bv};
    }

    const unsigned wofs = __builtin_amdgcn_readfirstlane(16384u + (unsigned)wid*1024u);
    float va0[16], va1[16];                  // single staging set (reused)

#define STAGE_W(p) do {                                                   \
    const u16* g = Wb + (p)*20480 + wid*512 + lane*8;                     \
    _Pragma("unroll")                                                     \
    for (int i = 0; i < 10; ++i) gll16(g + i*2048, wofs + i*4096); } while(0)
#define LOAD_A(p) do {                                                    \
    _Pragma("unroll")                                                     \
    for (int i = 0; i < 16; ++i) {                                        \
        const int c = i*4 + cpair;                                        \
        va0[i] = xb[(size_t)((p)*64 + c    )*HW_ + wql];                  \
        va1[i] = xb[(size_t)((p)*64 + c + 1)*HW_ + wql];                  \
    } } while(0)
#define WRITE_A() do {                                                    \
    _Pragma("unroll")                                                     \
    for (int i = 0; i < 16; ++i) {                                        \
        const int c = i*4 + cpair;                                        \
        const unsigned pk = (unsigned)f2b(va0[i]) | ((unsigned)f2b(va1[i]) << 16); \
        *(unsigned*)(void*)&ldsA[wql*64 + (((c >> 3) ^ (wql & 7)) << 3)   \
                                 + (c & 7)] = pk;                         \
    } } while(0)
#define MFMA_PHASE() do {                                                 \
    __builtin_amdgcn_s_setprio(1);                                        \
    _Pragma("unroll")                                                     \
    for (int ks = 0; ks < 2; ++ks) {                                      \
        s16x8 bf[5];                                                      \
        _Pragma("unroll")                                                 \
        for (int ct = 0; ct < 5; ++ct) {                                  \
            const int o = (ct*4 + wid)*16 + l15;                          \
            bf[ct] = *(const s16x8*)(const void*)                         \
                     &ldsW[o*64 + (((ks*4 + q) ^ (o & 7)) << 3)];         \
        }                                                                 \
        _Pragma("unroll")                                                 \
        for (int r = 0; r < 8; ++r) {                                     \
            const int w = r*16 + l15;                                     \
            const s16x8 af = *(const s16x8*)(const void*)                 \
                     &ldsA[w*64 + (((ks*4 + q) ^ (w & 7)) << 3)];         \
            _Pragma("unroll")                                             \
            for (int ct = 0; ct < 5; ++ct)                                \
                acc[r][ct] = MFMA_BF16(af, bf[ct], acc[r][ct], 0, 0, 0);  \
        }                                                                 \
    }                                                                     \
    __builtin_amdgcn_s_setprio(0); } while(0)

    // prologue: A0 loads oldest; W0 glls fly past WRITE_A's data-wait
    LOAD_A(0);
    STAGE_W(0);
    WRITE_A();                               // waits va (oldest), glls keep flying
    LOAD_A(1);
    asm volatile("s_waitcnt lgkmcnt(0) vmcnt(32)" ::: "memory");  // W0 + A0-lds done
    __builtin_amdgcn_s_barrier();
    MFMA_PHASE();                            // phase 0
    asm volatile("s_waitcnt lgkmcnt(0)" ::: "memory");
    __builtin_amdgcn_s_barrier();
    STAGE_W(1);                              // glls before A2 loads (vmcnt order)
    WRITE_A();                               // A1 -> LDS
    LOAD_A(2);
    asm volatile("s_waitcnt lgkmcnt(0) vmcnt(32)" ::: "memory");  // W1 + A1-lds done
    __builtin_amdgcn_s_barrier();
    MFMA_PHASE();                            // phase 1
    asm volatile("s_waitcnt lgkmcnt(0)" ::: "memory");
    __builtin_amdgcn_s_barrier();
    STAGE_W(2);
    WRITE_A();                               // A2 -> LDS
    asm volatile("s_waitcnt lgkmcnt(0) vmcnt(0)" ::: "memory");   // W2 done
    __builtin_amdgcn_s_barrier();
    MFMA_PHASE();                            // phase 2
    asm volatile("s_waitcnt lgkmcnt(0)" ::: "memory");
    __builtin_amdgcn_s_barrier();

    // ---- epilogue: Q/K direct (32B segments), V via LDS transpose (reuse lds)
    {
        const int oc = wid*16 + l15;
        #pragma unroll
        for (int r = 0; r < 8; ++r)
            #pragma unroll
            for (int rg = 0; rg < 4; ++rg) {
                const int w = r*16 + q*4 + rg;
                const size_t base = ((size_t)(b*W_ + w)*H_ + h)*CQK_ + oc;
                Qc[base] = f2b(acc[r][0][rg]);
                Kc[base] = f2b(acc[r][1][rg]);
            }
    }
    u16* ldsVe = lds;                        // 24576 u16 (48 KB)
    #pragma unroll
    for (int ct = 2; ct < 5; ++ct) {
        const int c = (ct - 2)*64 + wid*16 + l15;
        #pragma unroll
        for (int r = 0; r < 8; ++r) {
            const int w0 = r*16 + q*4;
            u32x2 pk;
            pk.x = (unsigned)f2b(acc[r][ct][0]) | ((unsigned)f2b(acc[r][ct][1]) << 16);
            pk.y = (unsigned)f2b(acc[r][ct][2]) | ((unsigned)f2b(acc[r][ct][3]) << 16);
            *(u32x2*)(void*)&ldsVe[c*128 + (((w0 >> 3) ^ (c & 7)) << 3) + (w0 & 7)] = pk;
        }
    }
    asm volatile("s_waitcnt lgkmcnt(0)" ::: "memory");
    __builtin_amdgcn_s_barrier();
    #pragma unroll
    for (int i = 0; i < 12; ++i) {
        const int idx = i*256 + t;
        const int c = idx >> 4, j = idx & 15;
        const s16x8 v = *(const s16x8*)(const void*)&ldsVe[c*128 + j*8];
        *(s16x8*)(void*)&Vn[(size_t)(b*C_ + c)*HW_ + h*W_ + ((j ^ (c & 7)) << 3)] = v;
    }
#undef STAGE_W
#undef LOAD_A
#undef WRITE_A
#undef MFMA_PHASE
}

// ------------------------------------------- V transpose: [c][h][w]->[c][w][h]
__global__ __launch_bounds__(256) void ktrv(
    const u16* __restrict__ Vn, u16* __restrict__ Vc)
{
    __shared__ u16 T[128*128];
    const int c = blockIdx.x, b = blockIdx.y;
    const u16* src = Vn + (size_t)(b*C_ + c)*HW_;
    u16*       dst = Vc + (size_t)(b*C_ + c)*HW_;
    const int t = threadIdx.x;
    for (int idx = t; idx < 128*16; idx += 256) {
        const int hh = idx >> 4, o = idx & 15;
        s16x8 v = *(const s16x8*)(void*)(src + hh*128 + o*8);
        *(s16x8*)(void*)(T + hh*128 + ((o ^ (hh & 7)) << 3)) = v;
    }
    __syncthreads();
    const int w = t & 127, half = t >> 7;
    for (int seg = 0; seg < 8; ++seg) {
        const int h0 = half*64 + seg*8;
        s16x8 pk;
        #pragma unroll
        for (int k = 0; k < 8; ++k) {
            const int hh = h0 + k;
            const int chunk = (w >> 3) ^ (hh & 7);
            pk[k] = (short)T[hh*128 + (chunk << 3) + (w & 7)];
        }
        *(s16x8*)(void*)(dst + w*128 + h0) = pk;
    }
}

// ------------- column attention (per b,w): O2 + Mh,Sh [512 thr, 48KB, (512,4)]
__global__ __launch_bounds__(512, 4) void kC(
    const u16* __restrict__ Qc, const u16* __restrict__ Kc,
    const u16* __restrict__ Vc,
    u16* __restrict__ O2, float* __restrict__ Mh, float* __restrict__ Sh)
{
    extern __shared__ char smem[];
    char* ldsK = smem;                       // 16K staging (dies at P)
    char* ldsP = smem;                       // 32K
    char* ldsV = smem + 32768;               // 16K V chunk
    const int w = blockIdx.x, b = blockIdx.y;
    const int t = threadIdx.x, lane = t & 63, wid = t >> 6;
    const int l15 = lane & 15, q = lane >> 4;
    const int arow = (wid << 4) + l15;

    // ---- Q direct to regs (wave-private score rows; linear global layout)
    const u16* qrow = Qc + ((size_t)(b*W_ + w)*H_ + arow)*CQK_;
    s16x8 qf0 = *(const s16x8*)(const void*)(qrow + q*8);
    s16x8 qf1 = *(const s16x8*)(const void*)(qrow + (4 + q)*8);
    // ---- V chunk1 (c 64..127) into regs
    s16x8 vh[2];
    #pragma unroll
    for (int i = 0; i < 2; ++i) {
        const int idx = i*512 + t;
        const int c = 64 + (idx >> 4), o = idx & 15;
        vh[i] = *(const s16x8*)(const void*)
                (Vc + ((size_t)(b*C_ + c)*W_ + w)*H_ + o*8);
    }
    // ---- K -> LDS, V chunk0 -> LDS
    {
        const u16* ksrc = Kc + (size_t)(b*W_ + w)*H_*CQK_;
        for (int idx = t; idx < 1024; idx += 512) {
            const int r = idx >> 3, o = idx & 7;
            *(s16x8*)(ldsK + r*128 + ((o ^ (r & 7)) << 4)) =
                *(const s16x8*)(const void*)(ksrc + idx*8);
        }
    }
    for (int idx = t; idx < 1024; idx += 512) {
        const int lc = idx >> 4, o = idx & 15;
        *(s16x8*)(ldsV + lc*256 + ((o ^ (lc & 7)) << 4)) =
            *(const s16x8*)(const void*)
            (Vc + ((size_t)(b*C_ + lc)*W_ + w)*H_ + o*8);
    }
    __syncthreads();

    // ---- scores: e_h[h][g]
    f32x4 accS[8];
    #pragma unroll
    for (int i = 0; i < 8; ++i) accS[i] = (f32x4){0.f,0.f,0.f,0.f};
    #pragma unroll
    for (int ks = 0; ks < 2; ++ks) {
        const int ch = ks*4 + q;
        const s16x8 af = ks ? qf1 : qf0;
        #pragma unroll
        for (int gt = 0; gt < 8; ++gt) {
            const int br = (gt << 4) + l15;
            s16x8 bf = *(const s16x8*)(ldsK + br*128 + ((ch ^ (br & 7)) << 4));
            accS[gt] = MFMA_BF16(af, bf, accS[gt], 0, 0, 0);
        }
    }
    __syncthreads();                         // K dead -> P region writable

    // ---- diag mask, stats, P (wave-local rows)
    #pragma unroll
    for (int r = 0; r < 4; ++r) {
        const int hh = (wid << 4) + (q << 2) + r;
        #pragma unroll
        for (int gt = 0; gt < 8; ++gt)
            if ((gt << 4) + l15 == hh) accS[gt][r] = -3.0e38f;
        float m = -3.0e38f;
        #pragma unroll
        for (int gt = 0; gt < 8; ++gt) m = fmaxf(m, accS[gt][r]);
        m = fmaxf(m, __shfl_xor(m, 1)); m = fmaxf(m, __shfl_xor(m, 2));
        m = fmaxf(m, __shfl_xor(m, 4)); m = fmaxf(m, __shfl_xor(m, 8));
        float s = 0.f;
        #pragma unroll
        for (int gt = 0; gt < 8; ++gt) {
            const float e = __expf(accS[gt][r] - m);
            s += e;
            const int g = (gt << 4) + l15;
            *(u16*)(ldsP + hh*256 + (((g >> 3) ^ (hh & 7)) << 4) + (g & 7)*2)
                = f2b(e);
        }
        s += __shfl_xor(s, 1); s += __shfl_xor(s, 2);
        s += __shfl_xor(s, 4); s += __shfl_xor(s, 8);
        if (l15 == 0) {
            Mh[(b*W_ + w)*H_ + hh] = m;
            Sh[(b*W_ + w)*H_ + hh] = s;
        }
    }
    // (no barrier: P wave-local, V0 staged since first barrier)

#define KC_PV(accv) do {                                                  \
    _Pragma("unroll")                                                     \
    for (int ks = 0; ks < 4; ++ks) {                                      \
        const int ch = ks*4 + q;                                          \
        s16x8 afp = *(const s16x8*)(ldsP + arow*256 + ((ch ^ (arow & 7)) << 4)); \
        _Pragma("unroll")                                                 \
        for (int ct = 0; ct < 4; ++ct) {                                  \
            const int vr = (ct << 4) + l15;                               \
            s16x8 bfv = *(const s16x8*)(ldsV + vr*256 + ((ch ^ (vr & 7)) << 4)); \
            accv[ct] = MFMA_BF16(afp, bfv, accv[ct], 0, 0, 0);            \
        }                                                                 \
    } } while(0)
#define KC_O2W(accv, cb) do {                                             \
    _Pragma("unroll")                                                     \
    for (int ct = 0; ct < 4; ++ct) {                                      \
        const int c = (cb) + (ct << 4) + l15;                             \
        _Pragma("unroll")                                                 \
        for (int r = 0; r < 4; ++r) {                                     \
            const int hh = (wid << 4) + (q << 2) + r;                     \
            O2[((size_t)(b*H_ + hh)*W_ + w)*C_ + c] = f2b(accv[ct][r]);   \
        }                                                                 \
    } } while(0)

    f32x4 accO[4];
    #pragma unroll
    for (int i = 0; i < 4; ++i) accO[i] = (f32x4){0.f,0.f,0.f,0.f};
    KC_PV(accO);                             // chunk0 (c 0..63)
    __syncthreads();                         // V0 reads done
    #pragma unroll
    for (int i = 0; i < 2; ++i) {            // dsw V1; reload vh <- V2
        const int idx = i*512 + t;
        const int lc = idx >> 4, o = idx & 15;
        *(s16x8*)(ldsV + lc*256 + ((o ^ (lc & 7)) << 4)) = vh[i];
    }
    #pragma unroll
    for (int i = 0; i < 2; ++i) {
        const int idx = i*512 + t;
        const int c = 128 + (idx >> 4), o = idx & 15;
        vh[i] = *(const s16x8*)(const void*)
                (Vc + ((size_t)(b*C_ + c)*W_ + w)*H_ + o*8);
    }
    __syncthreads();                         // V1 visible
    KC_O2W(accO, 0);
    #pragma unroll
    for (int i = 0; i < 4; ++i) accO[i] = (f32x4){0.f,0.f,0.f,0.f};
    KC_PV(accO);                             // chunk1 (c 64..127)
    __syncthreads();                         // V1 reads done
    #pragma unroll
    for (int i = 0; i < 2; ++i) {            // dsw V2
        const int idx = i*512 + t;
        const int lc = idx >> 4, o = idx & 15;
        *(s16x8*)(ldsV + lc*256 + ((o ^ (lc & 7)) << 4)) = vh[i];
    }
    __syncthreads();                         // V2 visible
    KC_O2W(accO, 64);
    #pragma unroll
    for (int i = 0; i < 4; ++i) accO[i] = (f32x4){0.f,0.f,0.f,0.f};
    KC_PV(accO);                             // chunk2 (c 128..191)
    KC_O2W(accO, 128);
#undef KC_PV
#undef KC_O2W
}

// ---- row attention + fused final (per b,h) [512 thr, 49KB LDS, (512,4)]
__global__ __launch_bounds__(512, 4) void kR(
    const u16* __restrict__ Qc, const u16* __restrict__ Kc,
    const u16* __restrict__ Vn, const u16* __restrict__ O2,
    const float* __restrict__ Mh, const float* __restrict__ Sh,
    const float* __restrict__ x, const float* __restrict__ gamma,
    float* __restrict__ out)
{
    extern __shared__ char smem[];
    char*  ldsK  = smem;                     // 16K staging (dies at P)
    char*  ldsP  = smem;                     // 32K
    char*  ldsV  = smem + 32768;             // 16K V chunk
    float* sScw  = (float*)(smem + 49152);   // 512B
    float* sSch  = (float*)(smem + 49664);   // 512B
    const int h = blockIdx.x, b = blockIdx.y;
    const int t = threadIdx.x, lane = t & 63, wid = t >> 6;
    const int l15 = lane & 15, q = lane >> 4;
    const int arow = (wid << 4) + l15;       // score row / P row (w)
    const int wbase = (wid << 4) + (q << 2); // this thread's 4 w's (D rows)
    const float gam = gamma[0];

    // ---- Q direct to regs
    const u16* qrow = Qc + ((size_t)(b*W_ + arow)*H_ + h)*CQK_;
    s16x8 qf0 = *(const s16x8*)(const void*)(qrow + q*8);
    s16x8 qf1 = *(const s16x8*)(const void*)(qrow + (4 + q)*8);
    // ---- V chunk1 (c 64..127) into regs (the ONLY reg-carried prefetch)
    s16x8 vh[2];
    #pragma unroll
    for (int i = 0; i < 2; ++i) {
        const int idx = i*512 + t;
        const int c = 64 + (idx >> 4), o = idx & 15;
        vh[i] = *(const s16x8*)(const void*)
                (Vn + (size_t)(b*C_ + c)*HW_ + h*W_ + o*8);
    }
    // ---- K -> LDS, V chunk0 -> LDS
    for (int idx = t; idx < 1024; idx += 512) {
        const int r = idx >> 3, o = idx & 7;
        *(s16x8*)(ldsK + r*128 + ((o ^ (r & 7)) << 4)) =
            *(const s16x8*)(const void*)
            (Kc + ((size_t)(b*W_ + r)*H_ + h)*CQK_ + o*8);
    }
    for (int idx = t; idx < 1024; idx += 512) {
        const int lc = idx >> 4, o = idx & 15;
        *(s16x8*)(ldsV + lc*256 + ((o ^ (lc & 7)) << 4)) =
            *(const s16x8*)(const void*)
            (Vn + (size_t)(b*C_ + lc)*HW_ + h*W_ + o*8);
    }
    __syncthreads();

    // ---- scores: e_w[w][v]
    f32x4 accS[8];
    #pragma unroll
    for (int i = 0; i < 8; ++i) accS[i] = (f32x4){0.f,0.f,0.f,0.f};
    #pragma unroll
    for (int ks = 0; ks < 2; ++ks) {
        const int ch = ks*4 + q;
        const s16x8 af = ks ? qf1 : qf0;
        #pragma unroll
        for (int vt = 0; vt < 8; ++vt) {
            const int br = (vt << 4) + l15;
            s16x8 bf = *(const s16x8*)(ldsK + br*128 + ((ch ^ (br & 7)) << 4));
            accS[vt] = MFMA_BF16(af, bf, accS[vt], 0, 0, 0);
        }
    }
    __syncthreads();                         // K dead -> P region writable

    // ---- stats, P (wave-local), merged scales (l15==0 lanes, wave-local)
    #pragma unroll
    for (int r = 0; r < 4; ++r) {
        const int ww = (wid << 4) + (q << 2) + r;
        float m = -3.0e38f;
        #pragma unroll
        for (int vt = 0; vt < 8; ++vt) m = fmaxf(m, accS[vt][r]);
        m = fmaxf(m, __shfl_xor(m, 1)); m = fmaxf(m, __shfl_xor(m, 2));
        m = fmaxf(m, __shfl_xor(m, 4)); m = fmaxf(m, __shfl_xor(m, 8));
        float s = 0.f;
        #pragma unroll
        for (int vt = 0; vt < 8; ++vt) {
            const float e = __expf(accS[vt][r] - m);
            s += e;
            const int v = (vt << 4) + l15;
            *(u16*)(ldsP + ww*256 + (((v >> 3) ^ (ww & 7)) << 4) + (v & 7)*2)
                = f2b(e);
        }
        s += __shfl_xor(s, 1); s += __shfl_xor(s, 2);
        s += __shfl_xor(s, 4); s += __shfl_xor(s, 8);
        if (l15 == 0) {                      // merge with column stats
            const float mh  = Mh[(b*W_ + ww)*H_ + h];
            const float shv = Sh[(b*W_ + ww)*H_ + h];
            const float M = fmaxf(mh, m);
            const float S = shv*__expf(mh - M) + s*__expf(m - M);
            sScw[ww] = __expf(m - M) / S;
            sSch[ww] = __expf(mh - M) / S;
        }
    }
    // (no barrier: P + scales wave-local; V0 ready since first barrier)
    float scw[4], sch[4];
    #pragma unroll
    for (int r = 0; r < 4; ++r) { scw[r] = sScw[wbase + r]; sch[r] = sSch[wbase + r]; }

    const u16* o2p = O2 + (size_t)(b*H_ + h)*W_*C_;

#define KR_PV(accv) do {                                                  \
    _Pragma("unroll")                                                     \
    for (int ks = 0; ks < 4; ++ks) {                                      \
        const int ch = ks*4 + q;                                          \
        s16x8 afp = *(const s16x8*)(ldsP + arow*256 + ((ch ^ (arow & 7)) << 4)); \
        _Pragma("unroll")                                                 \
        for (int ct = 0; ct < 4; ++ct) {                                  \
            const int vr = (ct << 4) + l15;                               \
            s16x8 bfv = *(const s16x8*)(ldsV + vr*256 + ((ch ^ (vr & 7)) << 4)); \
            accv[ct] = MFMA_BF16(afp, bfv, accv[ct], 0, 0, 0);            \
        }                                                                 \
    } } while(0)
// direct-read epilogue: no persistent prefetch arrays (VGPR discipline)
#define KR_EPI(k, accv) do {                                              \
    _Pragma("unroll")                                                     \
    for (int ct = 0; ct < 4; ++ct) {                                      \
        const int c = (k)*64 + (ct << 4) + l15;                           \
        const size_t ga = (size_t)(b*C_ + c)*HW_ + h*W_ + wbase;          \
        const f32x4 xv = *(const f32x4*)(const void*)(x + ga);            \
        f32x4 res;                                                        \
        _Pragma("unroll")                                                 \
        for (int r = 0; r < 4; ++r) {                                     \
            const float o2 = b2f(o2p[(size_t)(wbase + r)*C_ + c]);        \
            res[r] = gam*(accv[ct][r]*scw[r] + o2*sch[r]) + xv[r];        \
        }                                                                 \
        *(f32x4*)(void*)(out + ga) = res;                                 \
    } } while(0)

    f32x4 accO[4];
    #pragma unroll
    for (int i = 0; i < 4; ++i) accO[i] = (f32x4){0.f,0.f,0.f,0.f};
    KR_PV(accO);                             // chunk0 (c 0..63)
    __syncthreads();                         // V0 reads done
    #pragma unroll
    for (int i = 0; i < 2; ++i) {            // dsw V1; reload vh <- V2
        const int idx = i*512 + t;
        const int lc = idx >> 4, o = idx & 15;
        *(s16x8*)(ldsV + lc*256 + ((o ^ (lc & 7)) << 4)) = vh[i];
    }
    #pragma unroll
    for (int i = 0; i < 2; ++i) {
        const int idx = i*512 + t;
        const int c = 128 + (idx >> 4), o = idx & 15;
        vh[i] = *(const s16x8*)(const void*)
                (Vn + (size_t)(b*C_ + c)*HW_ + h*W_ + o*8);
    }
    KR_EPI(0, accO);                         // stores cover dsw drain
    __syncthreads();                         // V1 visible
    #pragma unroll
    for (int i = 0; i < 4; ++i) accO[i] = (f32x4){0.f,0.f,0.f,0.f};
    KR_PV(accO);                             // chunk1 (c 64..127)
    __syncthreads();                         // V1 reads done
    #pragma unroll
    for (int i = 0; i < 2; ++i) {            // dsw V2
        const int idx = i*512 + t;
        const int lc = idx >> 4, o = idx & 15;
        *(s16x8*)(ldsV + lc*256 + ((o ^ (lc & 7)) << 4)) = vh[i];
    }
    KR_EPI(1, accO);
    __syncthreads();                         // V2 visible
    #pragma unroll
    for (int i = 0; i < 4; ++i) accO[i] = (f32x4){0.f,0.f,0.f,0.f};
    KR_PV(accO);                             // chunk2 (c 128..191)
    KR_EPI(2, accO);
#undef KR_PV
#undef KR_EPI
}

extern "C" void kernel_launch(void* const* d_in, const int* in_sizes, int n_in,
                              void* d_out, int out_size, void* d_ws, size_t ws_size,
                              hipStream_t stream)
{
    const float* x  = (const float*)d_in[0];
    const float* Wq = (const float*)d_in[1];
    const float* bq = (const float*)d_in[2];
    const float* Wk = (const float*)d_in[3];
    const float* bk = (const float*)d_in[4];
    const float* Wv = (const float*)d_in[5];
    const float* bv = (const float*)d_in[6];
    const float* gm = (const float*)d_in[7];
    float* out = (float*)d_out;

    u16* Qc = (u16*)d_ws;
    u16* Kc = Qc + 8388608;
    u16* Vn = Kc + 8388608;
    u16* Vc = Vn + 25165824;
    u16* O2 = Vc + 25165824;                 // 25165824 u16
    float* Mh = (float*)(O2 + 25165824);
    float* Sh = Mh + 131072;
    u16*  Wb = (u16*)(Sh + 131072);          // 61440 u16
    float* Bb = (float*)(Wb + 61440);        // 320 f32

    hipLaunchKernelGGL(kwcast, dim3(320), dim3(256), 0, stream,
                       Wq, bq, Wk, bk, Wv, bv, Wb, Bb);
    hipLaunchKernelGGL(kprojM, dim3(H_, B_), dim3(256), 0, stream,
                       x, Wb, Bb, Qc, Kc, Vn);
    hipLaunchKernelGGL(ktrv, dim3(C_, B_), dim3(256), 0, stream, Vn, Vc);
    hipLaunchKernelGGL(kC, dim3(W_, B_), dim3(512), 49152, stream,
                       Qc, Kc, Vc, O2, Mh, Sh);
    hipLaunchKernelGGL(kR, dim3(H_, B_), dim3(512), 50176, stream,
                       Qc, Kc, Vn, O2, Mh, Sh, x, gm, out);
}

// Round 10
// 182.953 us; speedup vs baseline: 1.4201x; 1.0356x over previous
//
#include <hip/hip_runtime.h>
#include <math.h>

// RCC criss-cross attention, MFMA-bf16 pipeline. B=8, C=192, CQK=64, H=W=128.
//
//  kwcast : Wq|Wk|Wv fp32 -> Wb bf16 pre-swizzled per-phase LDS image; bias
//  kprojM : fused GEMM reading x fp32 directly; Q/K epilogue via LDS
//           transpose -> full-row 16B stores (was 64x 2B scalar/thread)
//  ktrv   : V transpose -> Vc [b][c][w][h]
//  kC     : per (b,w): e_h MFMA (diag) -> Mh,Sh; P -> PV MFMA -> O2 [b][h][w][c]
//  kR     : per (b,h): e_w MFMA -> merged scales; PV in 3 V-chunks;
//           ONE-phase-ahead x/O2 reg prefetch (r7 lesson: never 3-deep)
//
// REGISTER DISCIPLINE: (512,6) spills (r7/r8). Use (512,4); keep single-phase
// prefetch live ranges so peak stays < 128 VGPRs.

#define B_   8
#define C_   192
#define CQK_ 64
#define H_   128
#define W_   128
#define HW_  (H_*W_)

typedef unsigned short u16;
typedef __attribute__((ext_vector_type(8))) short    s16x8;
typedef __attribute__((ext_vector_type(4))) float    f32x4;
typedef __attribute__((ext_vector_type(2))) unsigned u32x2;
#define MFMA_BF16 __builtin_amdgcn_mfma_f32_16x16x32_bf16

__device__ __forceinline__ u16 f2b(float f) {
    unsigned u = __float_as_uint(f);
    return (u16)((u + 0x7fffu + ((u >> 16) & 1u)) >> 16);   // RNE
}
__device__ __forceinline__ float b2f(u16 v) {
    return __uint_as_float(((unsigned)v) << 16);
}
// raw global->LDS 16B/lane: LDS dest = m0 + lane*16 (wave-uniform m0)
__device__ __forceinline__ void gll16(const u16* gsrc, unsigned lds_byte) {
    asm volatile("s_mov_b32 m0, %1\n\t"
                 "global_load_lds_dwordx4 %0, off"
                 :: "v"(gsrc), "s"(lds_byte) : "memory");
}

// ------------------------------------------------ W -> bf16 pre-swizzled + bias
__global__ __launch_bounds__(256) void kwcast(
    const float* __restrict__ Wq, const float* __restrict__ bq,
    const float* __restrict__ Wk, const float* __restrict__ bk,
    const float* __restrict__ Wv, const float* __restrict__ bv,
    u16* __restrict__ Wb, float* __restrict__ Bb)
{
    const int o = blockIdx.x;                // 320 rows
    const float *row, *bias; int oo;
    if (o < 64)        { row = Wq; bias = bq; oo = o;       }
    else if (o < 128)  { row = Wk; bias = bk; oo = o - 64;  }
    else               { row = Wv; bias = bv; oo = o - 128; }
    const int t = threadIdx.x;
    if (t < C_) {
        const int p = t >> 6, cc = t & 63;
        Wb[p*20480 + o*64 + (((cc >> 3) ^ (o & 7)) << 3) + (cc & 7)]
            = f2b(row[oo*C_ + t]);
    }
    if (t == C_) Bb[o] = bias[oo];
}

// ------------------- fused MFMA projection GEMM (reads x fp32 directly)
// LDS u16 idx: ldsA [0,8192) = A tile; ldsW [8192,28672).
// Epilogue A: Q/K images at [0,16384). Epilogue B: V image at [0,24576).
__global__ __launch_bounds__(256, 2) void kprojM(
    const float* __restrict__ x,
    const u16* __restrict__ Wb, const float* __restrict__ Bb,
    u16* __restrict__ Qc, u16* __restrict__ Kc, u16* __restrict__ Vn)
{
    __shared__ u16 lds[28672];               // 56 KB
    u16* ldsA = lds;
    u16* ldsW = lds + 8192;
    const int h = blockIdx.x, b = blockIdx.y;
    const int t = threadIdx.x, lane = t & 63, wid = t >> 6;
    const int l15 = lane & 15, q = lane >> 4;
    const float* xb = x + (size_t)b*C_*HW_ + h*W_;
    const int wql = t & 127, cpair = (t >> 7) << 1;

    f32x4 acc[8][5];
    #pragma unroll
    for (int ct = 0; ct < 5; ++ct) {
        const float bv = Bb[(ct*4 + wid)*16 + l15];
        #pragma unroll
        for (int r = 0; r < 8; ++r) acc[r][ct] = (f32x4){bv, bv, bv, bv};
    }

    const unsigned wofs = __builtin_amdgcn_readfirstlane(16384u + (unsigned)wid*1024u);
    float va0[16], va1[16];                  // single staging set (reused)

#define STAGE_W(p) do {                                                   \
    const u16* g = Wb + (p)*20480 + wid*512 + lane*8;                     \
    _Pragma("unroll")                                                     \
    for (int i = 0; i < 10; ++i) gll16(g + i*2048, wofs + i*4096); } while(0)
#define LOAD_A(p) do {                                                    \
    _Pragma("unroll")                                                     \
    for (int i = 0; i < 16; ++i) {                                        \
        const int c = i*4 + cpair;                                        \
        va0[i] = xb[(size_t)((p)*64 + c    )*HW_ + wql];                  \
        va1[i] = xb[(size_t)((p)*64 + c + 1)*HW_ + wql];                  \
    } } while(0)
#define WRITE_A() do {                                                    \
    _Pragma("unroll")                                                     \
    for (int i = 0; i < 16; ++i) {                                        \
        const int c = i*4 + cpair;                                        \
        const unsigned pk = (unsigned)f2b(va0[i]) | ((unsigned)f2b(va1[i]) << 16); \
        *(unsigned*)(void*)&ldsA[wql*64 + (((c >> 3) ^ (wql & 7)) << 3)   \
                                 + (c & 7)] = pk;                         \
    } } while(0)
#define MFMA_PHASE() do {                                                 \
    __builtin_amdgcn_s_setprio(1);                                        \
    _Pragma("unroll")                                                     \
    for (int ks = 0; ks < 2; ++ks) {                                      \
        s16x8 bf[5];                                                      \
        _Pragma("unroll")                                                 \
        for (int ct = 0; ct < 5; ++ct) {                                  \
            const int o = (ct*4 + wid)*16 + l15;                          \
            bf[ct] = *(const s16x8*)(const void*)                         \
                     &ldsW[o*64 + (((ks*4 + q) ^ (o & 7)) << 3)];         \
        }                                                                 \
        _Pragma("unroll")                                                 \
        for (int r = 0; r < 8; ++r) {                                     \
            const int w = r*16 + l15;                                     \
            const s16x8 af = *(const s16x8*)(const void*)                 \
                     &ldsA[w*64 + (((ks*4 + q) ^ (w & 7)) << 3)];         \
            _Pragma("unroll")                                             \
            for (int ct = 0; ct < 5; ++ct)                                \
                acc[r][ct] = MFMA_BF16(af, bf[ct], acc[r][ct], 0, 0, 0);  \
        }                                                                 \
    }                                                                     \
    __builtin_amdgcn_s_setprio(0); } while(0)

    LOAD_A(0);
    STAGE_W(0);
    WRITE_A();
    LOAD_A(1);
    asm volatile("s_waitcnt lgkmcnt(0) vmcnt(32)" ::: "memory");  // W0 + A0-lds done
    __builtin_amdgcn_s_barrier();
    MFMA_PHASE();                            // phase 0
    asm volatile("s_waitcnt lgkmcnt(0)" ::: "memory");
    __builtin_amdgcn_s_barrier();
    STAGE_W(1);
    WRITE_A();                               // A1 -> LDS
    LOAD_A(2);
    asm volatile("s_waitcnt lgkmcnt(0) vmcnt(32)" ::: "memory");  // W1 + A1-lds done
    __builtin_amdgcn_s_barrier();
    MFMA_PHASE();                            // phase 1
    asm volatile("s_waitcnt lgkmcnt(0)" ::: "memory");
    __builtin_amdgcn_s_barrier();
    STAGE_W(2);
    WRITE_A();                               // A2 -> LDS
    asm volatile("s_waitcnt lgkmcnt(0) vmcnt(0)" ::: "memory");   // W2 done
    __builtin_amdgcn_s_barrier();
    MFMA_PHASE();                            // phase 2
    asm volatile("s_waitcnt lgkmcnt(0)" ::: "memory");
    __builtin_amdgcn_s_barrier();

    // ---- epilogue A: Q/K -> LDS image -> full-row 16B stores
    {
        u16* ldsQe = lds;                    // 8192 u16 (16 KB) [w][64c swz]
        u16* ldsKe = lds + 8192;             // 8192 u16
        const int oc = wid*16 + l15;
        #pragma unroll
        for (int r = 0; r < 8; ++r)
            #pragma unroll
            for (int rg = 0; rg < 4; ++rg) {
                const int w = r*16 + q*4 + rg;
                const int idx = w*64 + (((oc >> 3) ^ (w & 7)) << 3) + (oc & 7);
                ldsQe[idx] = f2b(acc[r][0][rg]);
                ldsKe[idx] = f2b(acc[r][1][rg]);
            }
        asm volatile("s_waitcnt lgkmcnt(0)" ::: "memory");
        __builtin_amdgcn_s_barrier();
        #pragma unroll
        for (int i = 0; i < 4; ++i) {
            const int idx = i*256 + t;       // 1024 granules, 32 rows/instr
            const int r = idx >> 3, j = idx & 7;
            const int so = r*64 + ((j ^ (r & 7)) << 3);
            const size_t gb = ((size_t)(b*W_ + r)*H_ + h)*CQK_ + j*8;
            *(s16x8*)(void*)&Qc[gb] = *(const s16x8*)(const void*)&ldsQe[so];
            *(s16x8*)(void*)&Kc[gb] = *(const s16x8*)(const void*)&ldsKe[so];
        }
        asm volatile("s_waitcnt lgkmcnt(0)" ::: "memory");
        __builtin_amdgcn_s_barrier();        // image reads done -> V may overwrite
    }
    // ---- epilogue B: V via LDS transpose (unchanged)
    u16* ldsVe = lds;                        // 24576 u16 (48 KB)
    #pragma unroll
    for (int ct = 2; ct < 5; ++ct) {
        const int c = (ct - 2)*64 + wid*16 + l15;
        #pragma unroll
        for (int r = 0; r < 8; ++r) {
            const int w0 = r*16 + q*4;
            u32x2 pk;
            pk.x = (unsigned)f2b(acc[r][ct][0]) | ((unsigned)f2b(acc[r][ct][1]) << 16);
            pk.y = (unsigned)f2b(acc[r][ct][2]) | ((unsigned)f2b(acc[r][ct][3]) << 16);
            *(u32x2*)(void*)&ldsVe[c*128 + (((w0 >> 3) ^ (c & 7)) << 3) + (w0 & 7)] = pk;
        }
    }
    asm volatile("s_waitcnt lgkmcnt(0)" ::: "memory");
    __builtin_amdgcn_s_barrier();
    #pragma unroll
    for (int i = 0; i < 12; ++i) {
        const int idx = i*256 + t;
        const int c = idx >> 4, j = idx & 15;
        const s16x8 v = *(const s16x8*)(const void*)&ldsVe[c*128 + j*8];
        *(s16x8*)(void*)&Vn[(size_t)(b*C_ + c)*HW_ + h*W_ + ((j ^ (c & 7)) << 3)] = v;
    }
#undef STAGE_W
#undef LOAD_A
#undef WRITE_A
#undef MFMA_PHASE
}

// ------------------------------------------- V transpose: [c][h][w]->[c][w][h]
__global__ __launch_bounds__(256) void ktrv(
    const u16* __restrict__ Vn, u16* __restrict__ Vc)
{
    __shared__ u16 T[128*128];
    const int c = blockIdx.x, b = blockIdx.y;
    const u16* src = Vn + (size_t)(b*C_ + c)*HW_;
    u16*       dst = Vc + (size_t)(b*C_ + c)*HW_;
    const int t = threadIdx.x;
    for (int idx = t; idx < 128*16; idx += 256) {
        const int hh = idx >> 4, o = idx & 15;
        s16x8 v = *(const s16x8*)(void*)(src + hh*128 + o*8);
        *(s16x8*)(void*)(T + hh*128 + ((o ^ (hh & 7)) << 3)) = v;
    }
    __syncthreads();
    const int w = t & 127, half = t >> 7;
    for (int seg = 0; seg < 8; ++seg) {
        const int h0 = half*64 + seg*8;
        s16x8 pk;
        #pragma unroll
        for (int k = 0; k < 8; ++k) {
            const int hh = h0 + k;
            const int chunk = (w >> 3) ^ (hh & 7);
            pk[k] = (short)T[hh*128 + (chunk << 3) + (w & 7)];
        }
        *(s16x8*)(void*)(dst + w*128 + h0) = pk;
    }
}

// ------------- column attention (per b,w): O2 + Mh,Sh [512 thr, 48KB, (512,4)]
__global__ __launch_bounds__(512, 4) void kC(
    const u16* __restrict__ Qc, const u16* __restrict__ Kc,
    const u16* __restrict__ Vc,
    u16* __restrict__ O2, float* __restrict__ Mh, float* __restrict__ Sh)
{
    extern __shared__ char smem[];
    char* ldsK = smem;                       // 16K staging (dies at P)
    char* ldsP = smem;                       // 32K
    char* ldsV = smem + 32768;               // 16K V chunk
    const int w = blockIdx.x, b = blockIdx.y;
    const int t = threadIdx.x, lane = t & 63, wid = t >> 6;
    const int l15 = lane & 15, q = lane >> 4;
    const int arow = (wid << 4) + l15;

    // ---- Q direct to regs (wave-private score rows; linear global layout)
    const u16* qrow = Qc + ((size_t)(b*W_ + w)*H_ + arow)*CQK_;
    s16x8 qf0 = *(const s16x8*)(const void*)(qrow + q*8);
    s16x8 qf1 = *(const s16x8*)(const void*)(qrow + (4 + q)*8);
    // ---- V chunk1 (c 64..127) into regs
    s16x8 vh[2];
    #pragma unroll
    for (int i = 0; i < 2; ++i) {
        const int idx = i*512 + t;
        const int c = 64 + (idx >> 4), o = idx & 15;
        vh[i] = *(const s16x8*)(const void*)
                (Vc + ((size_t)(b*C_ + c)*W_ + w)*H_ + o*8);
    }
    // ---- K -> LDS, V chunk0 -> LDS
    {
        const u16* ksrc = Kc + (size_t)(b*W_ + w)*H_*CQK_;
        for (int idx = t; idx < 1024; idx += 512) {
            const int r = idx >> 3, o = idx & 7;
            *(s16x8*)(ldsK + r*128 + ((o ^ (r & 7)) << 4)) =
                *(const s16x8*)(const void*)(ksrc + idx*8);
        }
    }
    for (int idx = t; idx < 1024; idx += 512) {
        const int lc = idx >> 4, o = idx & 15;
        *(s16x8*)(ldsV + lc*256 + ((o ^ (lc & 7)) << 4)) =
            *(const s16x8*)(const void*)
            (Vc + ((size_t)(b*C_ + lc)*W_ + w)*H_ + o*8);
    }
    __syncthreads();

    // ---- scores: e_h[h][g]
    f32x4 accS[8];
    #pragma unroll
    for (int i = 0; i < 8; ++i) accS[i] = (f32x4){0.f,0.f,0.f,0.f};
    #pragma unroll
    for (int ks = 0; ks < 2; ++ks) {
        const int ch = ks*4 + q;
        const s16x8 af = ks ? qf1 : qf0;
        #pragma unroll
        for (int gt = 0; gt < 8; ++gt) {
            const int br = (gt << 4) + l15;
            s16x8 bf = *(const s16x8*)(ldsK + br*128 + ((ch ^ (br & 7)) << 4));
            accS[gt] = MFMA_BF16(af, bf, accS[gt], 0, 0, 0);
        }
    }
    __syncthreads();                         // K dead -> P region writable

    // ---- diag mask, stats, P (wave-local rows)
    #pragma unroll
    for (int r = 0; r < 4; ++r) {
        const int hh = (wid << 4) + (q << 2) + r;
        #pragma unroll
        for (int gt = 0; gt < 8; ++gt)
            if ((gt << 4) + l15 == hh) accS[gt][r] = -3.0e38f;
        float m = -3.0e38f;
        #pragma unroll
        for (int gt = 0; gt < 8; ++gt) m = fmaxf(m, accS[gt][r]);
        m = fmaxf(m, __shfl_xor(m, 1)); m = fmaxf(m, __shfl_xor(m, 2));
        m = fmaxf(m, __shfl_xor(m, 4)); m = fmaxf(m, __shfl_xor(m, 8));
        float s = 0.f;
        #pragma unroll
        for (int gt = 0; gt < 8; ++gt) {
            const float e = __expf(accS[gt][r] - m);
            s += e;
            const int g = (gt << 4) + l15;
            *(u16*)(ldsP + hh*256 + (((g >> 3) ^ (hh & 7)) << 4) + (g & 7)*2)
                = f2b(e);
        }
        s += __shfl_xor(s, 1); s += __shfl_xor(s, 2);
        s += __shfl_xor(s, 4); s += __shfl_xor(s, 8);
        if (l15 == 0) {
            Mh[(b*W_ + w)*H_ + hh] = m;
            Sh[(b*W_ + w)*H_ + hh] = s;
        }
    }
    // (no barrier: P wave-local, V0 staged since first barrier)

#define KC_PV(accv) do {                                                  \
    _Pragma("unroll")                                                     \
    for (int ks = 0; ks < 4; ++ks) {                                      \
        const int ch = ks*4 + q;                                          \
        s16x8 afp = *(const s16x8*)(ldsP + arow*256 + ((ch ^ (arow & 7)) << 4)); \
        _Pragma("unroll")                                                 \
        for (int ct = 0; ct < 4; ++ct) {                                  \
            const int vr = (ct << 4) + l15;                               \
            s16x8 bfv = *(const s16x8*)(ldsV + vr*256 + ((ch ^ (vr & 7)) << 4)); \
            accv[ct] = MFMA_BF16(afp, bfv, accv[ct], 0, 0, 0);            \
        }                                                                 \
    } } while(0)
#define KC_O2W(accv, cb) do {                                             \
    _Pragma("unroll")                                                     \
    for (int ct = 0; ct < 4; ++ct) {                                      \
        const int c = (cb) + (ct << 4) + l15;                             \
        _Pragma("unroll")                                                 \
        for (int r = 0; r < 4; ++r) {                                     \
            const int hh = (wid << 4) + (q << 2) + r;                     \
            O2[((size_t)(b*H_ + hh)*W_ + w)*C_ + c] = f2b(accv[ct][r]);   \
        }                                                                 \
    } } while(0)

    f32x4 accO[4];
    #pragma unroll
    for (int i = 0; i < 4; ++i) accO[i] = (f32x4){0.f,0.f,0.f,0.f};
    KC_PV(accO);                             // chunk0 (c 0..63)
    __syncthreads();                         // V0 reads done
    #pragma unroll
    for (int i = 0; i < 2; ++i) {            // dsw V1; reload vh <- V2
        const int idx = i*512 + t;
        const int lc = idx >> 4, o = idx & 15;
        *(s16x8*)(ldsV + lc*256 + ((o ^ (lc & 7)) << 4)) = vh[i];
    }
    #pragma unroll
    for (int i = 0; i < 2; ++i) {
        const int idx = i*512 + t;
        const int c = 128 + (idx >> 4), o = idx & 15;
        vh[i] = *(const s16x8*)(const void*)
                (Vc + ((size_t)(b*C_ + c)*W_ + w)*H_ + o*8);
    }
    __syncthreads();                         // V1 visible
    KC_O2W(accO, 0);
    #pragma unroll
    for (int i = 0; i < 4; ++i) accO[i] = (f32x4){0.f,0.f,0.f,0.f};
    KC_PV(accO);                             // chunk1 (c 64..127)
    __syncthreads();                         // V1 reads done
    #pragma unroll
    for (int i = 0; i < 2; ++i) {            // dsw V2
        const int idx = i*512 + t;
        const int lc = idx >> 4, o = idx & 15;
        *(s16x8*)(ldsV + lc*256 + ((o ^ (lc & 7)) << 4)) = vh[i];
    }
    __syncthreads();                         // V2 visible
    KC_O2W(accO, 64);
    #pragma unroll
    for (int i = 0; i < 4; ++i) accO[i] = (f32x4){0.f,0.f,0.f,0.f};
    KC_PV(accO);                             // chunk2 (c 128..191)
    KC_O2W(accO, 128);
#undef KC_PV
#undef KC_O2W
}

// ---- row attention + fused final (per b,h) [512 thr, 49KB LDS, (512,4)]
__global__ __launch_bounds__(512, 4) void kR(
    const u16* __restrict__ Qc, const u16* __restrict__ Kc,
    const u16* __restrict__ Vn, const u16* __restrict__ O2,
    const float* __restrict__ Mh, const float* __restrict__ Sh,
    const float* __restrict__ x, const float* __restrict__ gamma,
    float* __restrict__ out)
{
    extern __shared__ char smem[];
    char*  ldsK  = smem;                     // 16K staging (dies at P)
    char*  ldsP  = smem;                     // 32K
    char*  ldsV  = smem + 32768;             // 16K V chunk
    float* sScw  = (float*)(smem + 49152);   // 512B
    float* sSch  = (float*)(smem + 49664);   // 512B
    const int h = blockIdx.x, b = blockIdx.y;
    const int t = threadIdx.x, lane = t & 63, wid = t >> 6;
    const int l15 = lane & 15, q = lane >> 4;
    const int arow = (wid << 4) + l15;       // score row / P row (w)
    const int wbase = (wid << 4) + (q << 2); // this thread's 4 w's (D rows)
    const float gam = gamma[0];

    // ---- Q direct to regs
    const u16* qrow = Qc + ((size_t)(b*W_ + arow)*H_ + h)*CQK_;
    s16x8 qf0 = *(const s16x8*)(const void*)(qrow + q*8);
    s16x8 qf1 = *(const s16x8*)(const void*)(qrow + (4 + q)*8);
    // ---- V chunk1 (c 64..127) into regs
    s16x8 vh[2];
    #pragma unroll
    for (int i = 0; i < 2; ++i) {
        const int idx = i*512 + t;
        const int c = 64 + (idx >> 4), o = idx & 15;
        vh[i] = *(const s16x8*)(const void*)
                (Vn + (size_t)(b*C_ + c)*HW_ + h*W_ + o*8);
    }
    // ---- K -> LDS, V chunk0 -> LDS
    for (int idx = t; idx < 1024; idx += 512) {
        const int r = idx >> 3, o = idx & 7;
        *(s16x8*)(ldsK + r*128 + ((o ^ (r & 7)) << 4)) =
            *(const s16x8*)(const void*)
            (Kc + ((size_t)(b*W_ + r)*H_ + h)*CQK_ + o*8);
    }
    for (int idx = t; idx < 1024; idx += 512) {
        const int lc = idx >> 4, o = idx & 15;
        *(s16x8*)(ldsV + lc*256 + ((o ^ (lc & 7)) << 4)) =
            *(const s16x8*)(const void*)
            (Vn + (size_t)(b*C_ + lc)*HW_ + h*W_ + o*8);
    }
    __syncthreads();

    // ---- scores: e_w[w][v]
    f32x4 accS[8];
    #pragma unroll
    for (int i = 0; i < 8; ++i) accS[i] = (f32x4){0.f,0.f,0.f,0.f};
    #pragma unroll
    for (int ks = 0; ks < 2; ++ks) {
        const int ch = ks*4 + q;
        const s16x8 af = ks ? qf1 : qf0;
        #pragma unroll
        for (int vt = 0; vt < 8; ++vt) {
            const int br = (vt << 4) + l15;
            s16x8 bf = *(const s16x8*)(ldsK + br*128 + ((ch ^ (br & 7)) << 4));
            accS[vt] = MFMA_BF16(af, bf, accS[vt], 0, 0, 0);
        }
    }
    __syncthreads();                         // K dead -> P region writable

    // ---- stats, P (wave-local), merged scales (l15==0 lanes, wave-local)
    #pragma unroll
    for (int r = 0; r < 4; ++r) {
        const int ww = (wid << 4) + (q << 2) + r;
        float m = -3.0e38f;
        #pragma unroll
        for (int vt = 0; vt < 8; ++vt) m = fmaxf(m, accS[vt][r]);
        m = fmaxf(m, __shfl_xor(m, 1)); m = fmaxf(m, __shfl_xor(m, 2));
        m = fmaxf(m, __shfl_xor(m, 4)); m = fmaxf(m, __shfl_xor(m, 8));
        float s = 0.f;
        #pragma unroll
        for (int vt = 0; vt < 8; ++vt) {
            const float e = __expf(accS[vt][r] - m);
            s += e;
            const int v = (vt << 4) + l15;
            *(u16*)(ldsP + ww*256 + (((v >> 3) ^ (ww & 7)) << 4) + (v & 7)*2)
                = f2b(e);
        }
        s += __shfl_xor(s, 1); s += __shfl_xor(s, 2);
        s += __shfl_xor(s, 4); s += __shfl_xor(s, 8);
        if (l15 == 0) {                      // merge with column stats
            const float mh  = Mh[(b*W_ + ww)*H_ + h];
            const float shv = Sh[(b*W_ + ww)*H_ + h];
            const float M = fmaxf(mh, m);
            const float S = shv*__expf(mh - M) + s*__expf(m - M);
            sScw[ww] = __expf(m - M) / S;
            sSch[ww] = __expf(mh - M) / S;
        }
    }
    // (no barrier: P + scales wave-local; V0 ready since first barrier)
    float scw[4], sch[4];
    #pragma unroll
    for (int r = 0; r < 4; ++r) { scw[r] = sScw[wbase + r]; sch[r] = sSch[wbase + r]; }

    const u16* o2p = O2 + (size_t)(b*H_ + h)*W_*C_;

#define KR_PV(accv) do {                                                  \
    _Pragma("unroll")                                                     \
    for (int ks = 0; ks < 4; ++ks) {                                      \
        const int ch = ks*4 + q;                                          \
        s16x8 afp = *(const s16x8*)(ldsP + arow*256 + ((ch ^ (arow & 7)) << 4)); \
        _Pragma("unroll")                                                 \
        for (int ct = 0; ct < 4; ++ct) {                                  \
            const int vr = (ct << 4) + l15;                               \
            s16x8 bfv = *(const s16x8*)(ldsV + vr*256 + ((ch ^ (vr & 7)) << 4)); \
            accv[ct] = MFMA_BF16(afp, bfv, accv[ct], 0, 0, 0);            \
        }                                                                 \
    } } while(0)
// ONE-phase-ahead prefetch: xp/o2r live only PREF(k)..EPI(k) (no r7 3-deep)
#define KR_PREF(k) do {                                                   \
    _Pragma("unroll")                                                     \
    for (int ct = 0; ct < 4; ++ct) {                                      \
        const int c = (k)*64 + (ct << 4) + l15;                           \
        xp[ct] = *(const f32x4*)(const void*)                             \
                 (x + (size_t)(b*C_ + c)*HW_ + h*W_ + wbase);             \
        _Pragma("unroll")                                                 \
        for (int r = 0; r < 4; ++r)                                       \
            o2r[ct][r] = o2p[(size_t)(wbase + r)*C_ + c];                 \
    } } while(0)
#define KR_EPI(k, accv) do {                                              \
    _Pragma("unroll")                                                     \
    for (int ct = 0; ct < 4; ++ct) {                                      \
        const int c = (k)*64 + (ct << 4) + l15;                           \
        const size_t ga = (size_t)(b*C_ + c)*HW_ + h*W_ + wbase;          \
        f32x4 res;                                                        \
        _Pragma("unroll")                                                 \
        for (int r = 0; r < 4; ++r)                                       \
            res[r] = gam*(accv[ct][r]*scw[r] + b2f(o2r[ct][r])*sch[r]) + xp[ct][r]; \
        *(f32x4*)(void*)(out + ga) = res;                                 \
    } } while(0)

    f32x4 xp[4]; u16 o2r[4][4];
    f32x4 accO[4];
    KR_PREF(0);                              // lands under PV0
    #pragma unroll
    for (int i = 0; i < 4; ++i) accO[i] = (f32x4){0.f,0.f,0.f,0.f};
    KR_PV(accO);                             // chunk0 (c 0..63)
    __syncthreads();                         // V0 reads done
    #pragma unroll
    for (int i = 0; i < 2; ++i) {            // dsw V1; reload vh <- V2
        const int idx = i*512 + t;
        const int lc = idx >> 4, o = idx & 15;
        *(s16x8*)(ldsV + lc*256 + ((o ^ (lc & 7)) << 4)) = vh[i];
    }
    #pragma unroll
    for (int i = 0; i < 2; ++i) {
        const int idx = i*512 + t;
        const int c = 128 + (idx >> 4), o = idx & 15;
        vh[i] = *(const s16x8*)(const void*)
                (Vn + (size_t)(b*C_ + c)*HW_ + h*W_ + o*8);
    }
    KR_EPI(0, accO);                         // stores cover dsw drain
    KR_PREF(1);                              // lands under PV1
    __syncthreads();                         // V1 visible
    #pragma unroll
    for (int i = 0; i < 4; ++i) accO[i] = (f32x4){0.f,0.f,0.f,0.f};
    KR_PV(accO);                             // chunk1 (c 64..127)
    __syncthreads();                         // V1 reads done
    #pragma unroll
    for (int i = 0; i < 2; ++i) {            // dsw V2
        const int idx = i*512 + t;
        const int lc = idx >> 4, o = idx & 15;
        *(s16x8*)(ldsV + lc*256 + ((o ^ (lc & 7)) << 4)) = vh[i];
    }
    KR_EPI(1, accO);
    KR_PREF(2);                              // lands under PV2
    __syncthreads();                         // V2 visible
    #pragma unroll
    for (int i = 0; i < 4; ++i) accO[i] = (f32x4){0.f,0.f,0.f,0.f};
    KR_PV(accO);                             // chunk2 (c 128..191)
    KR_EPI(2, accO);
#undef KR_PV
#undef KR_PREF
#undef KR_EPI
}

extern "C" void kernel_launch(void* const* d_in, const int* in_sizes, int n_in,
                              void* d_out, int out_size, void* d_ws, size_t ws_size,
                              hipStream_t stream)
{
    const float* x  = (const float*)d_in[0];
    const float* Wq = (const float*)d_in[1];
    const float* bq = (const float*)d_in[2];
    const float* Wk = (const float*)d_in[3];
    const float* bk = (const float*)d_in[4];
    const float* Wv = (const float*)d_in[5];
    const float* bv = (const float*)d_in[6];
    const float* gm = (const float*)d_in[7];
    float* out = (float*)d_out;

    u16* Qc = (u16*)d_ws;
    u16* Kc = Qc + 8388608;
    u16* Vn = Kc + 8388608;
    u16* Vc = Vn + 25165824;
    u16* O2 = Vc + 25165824;                 // 25165824 u16
    float* Mh = (float*)(O2 + 25165824);
    float* Sh = Mh + 131072;
    u16*  Wb = (u16*)(Sh + 131072);          // 61440 u16
    float* Bb = (float*)(Wb + 61440);        // 320 f32

    hipLaunchKernelGGL(kwcast, dim3(320), dim3(256), 0, stream,
                       Wq, bq, Wk, bk, Wv, bv, Wb, Bb);
    hipLaunchKernelGGL(kprojM, dim3(H_, B_), dim3(256), 0, stream,
                       x, Wb, Bb, Qc, Kc, Vn);
    hipLaunchKernelGGL(ktrv, dim3(C_, B_), dim3(256), 0, stream, Vn, Vc);
    hipLaunchKernelGGL(kC, dim3(W_, B_), dim3(512), 49152, stream,
                       Qc, Kc, Vc, O2, Mh, Sh);
    hipLaunchKernelGGL(kR, dim3(H_, B_), dim3(512), 50176, stream,
                       Qc, Kc, Vn, O2, Mh, Sh, x, gm, out);
}

// Round 11
// 181.170 us; speedup vs baseline: 1.4341x; 1.0098x over previous
//
#include <hip/hip_runtime.h>
#include <math.h>

// RCC criss-cross attention, MFMA-bf16 pipeline. B=8, C=192, CQK=64, H=W=128.
//
//  kwcast : Wq|Wk|Wv fp32 -> Wb bf16 pre-swizzled per-phase LDS image; bias
//  kprojM : fused GEMM reading x fp32 directly; Q/K epilogue via LDS transpose
//  ktrv   : V transpose -> Vc [b][c][w][h]
//  kC     : per (b,w): e_h MFMA (diag) -> Mh,Sh; P -> PV MFMA -> O2 [b][h][w][c]
//  kR     : per (b,h): e_w MFMA -> merged scales; PV in 3 V-chunks; fused final
//
// kC/kR at launch_bounds(512,6) -> 3 blocks/CU (24 waves). Register budget
// 85/thread; to fit without spills (r7/r8 lesson):
//   - vh[2] V-prefetch issued AFTER stats (latency hides under PV0 MFMAs,
//     keeps prologue live-set small)
//   - direct-read epilogue (no prefetch arrays; r10 showed prefetch ~3us,
//     a spill costs 10-75us)
// Gate: if kR hbm_bytes > ~240MB it spilled -> (512,6) closed, revert.

#define B_   8
#define C_   192
#define CQK_ 64
#define H_   128
#define W_   128
#define HW_  (H_*W_)

typedef unsigned short u16;
typedef __attribute__((ext_vector_type(8))) short    s16x8;
typedef __attribute__((ext_vector_type(4))) float    f32x4;
typedef __attribute__((ext_vector_type(2))) unsigned u32x2;
#define MFMA_BF16 __builtin_amdgcn_mfma_f32_16x16x32_bf16

__device__ __forceinline__ u16 f2b(float f) {
    unsigned u = __float_as_uint(f);
    return (u16)((u + 0x7fffu + ((u >> 16) & 1u)) >> 16);   // RNE
}
__device__ __forceinline__ float b2f(u16 v) {
    return __uint_as_float(((unsigned)v) << 16);
}
// raw global->LDS 16B/lane: LDS dest = m0 + lane*16 (wave-uniform m0)
__device__ __forceinline__ void gll16(const u16* gsrc, unsigned lds_byte) {
    asm volatile("s_mov_b32 m0, %1\n\t"
                 "global_load_lds_dwordx4 %0, off"
                 :: "v"(gsrc), "s"(lds_byte) : "memory");
}

// ------------------------------------------------ W -> bf16 pre-swizzled + bias
__global__ __launch_bounds__(256) void kwcast(
    const float* __restrict__ Wq, const float* __restrict__ bq,
    const float* __restrict__ Wk, const float* __restrict__ bk,
    const float* __restrict__ Wv, const float* __restrict__ bv,
    u16* __restrict__ Wb, float* __restrict__ Bb)
{
    const int o = blockIdx.x;                // 320 rows
    const float *row, *bias; int oo;
    if (o < 64)        { row = Wq; bias = bq; oo = o;       }
    else if (o < 128)  { row = Wk; bias = bk; oo = o - 64;  }
    else               { row = Wv; bias = bv; oo = o - 128; }
    const int t = threadIdx.x;
    if (t < C_) {
        const int p = t >> 6, cc = t & 63;
        Wb[p*20480 + o*64 + (((cc >> 3) ^ (o & 7)) << 3) + (cc & 7)]
            = f2b(row[oo*C_ + t]);
    }
    if (t == C_) Bb[o] = bias[oo];
}

// ------------------- fused MFMA projection GEMM (reads x fp32 directly)
__global__ __launch_bounds__(256, 2) void kprojM(
    const float* __restrict__ x,
    const u16* __restrict__ Wb, const float* __restrict__ Bb,
    u16* __restrict__ Qc, u16* __restrict__ Kc, u16* __restrict__ Vn)
{
    __shared__ u16 lds[28672];               // 56 KB
    u16* ldsA = lds;
    u16* ldsW = lds + 8192;
    const int h = blockIdx.x, b = blockIdx.y;
    const int t = threadIdx.x, lane = t & 63, wid = t >> 6;
    const int l15 = lane & 15, q = lane >> 4;
    const float* xb = x + (size_t)b*C_*HW_ + h*W_;
    const int wql = t & 127, cpair = (t >> 7) << 1;

    f32x4 acc[8][5];
    #pragma unroll
    for (int ct = 0; ct < 5; ++ct) {
        const float bv = Bb[(ct*4 + wid)*16 + l15];
        #pragma unroll
        for (int r = 0; r < 8; ++r) acc[r][ct] = (f32x4){bv, bv, bv, bv};
    }

    const unsigned wofs = __builtin_amdgcn_readfirstlane(16384u + (unsigned)wid*1024u);
    float va0[16], va1[16];                  // single staging set (reused)

#define STAGE_W(p) do {                                                   \
    const u16* g = Wb + (p)*20480 + wid*512 + lane*8;                     \
    _Pragma("unroll")                                                     \
    for (int i = 0; i < 10; ++i) gll16(g + i*2048, wofs + i*4096); } while(0)
#define LOAD_A(p) do {                                                    \
    _Pragma("unroll")                                                     \
    for (int i = 0; i < 16; ++i) {                                        \
        const int c = i*4 + cpair;                                        \
        va0[i] = xb[(size_t)((p)*64 + c    )*HW_ + wql];                  \
        va1[i] = xb[(size_t)((p)*64 + c + 1)*HW_ + wql];                  \
    } } while(0)
#define WRITE_A() do {                                                    \
    _Pragma("unroll")                                                     \
    for (int i = 0; i < 16; ++i) {                                        \
        const int c = i*4 + cpair;                                        \
        const unsigned pk = (unsigned)f2b(va0[i]) | ((unsigned)f2b(va1[i]) << 16); \
        *(unsigned*)(void*)&ldsA[wql*64 + (((c >> 3) ^ (wql & 7)) << 3)   \
                                 + (c & 7)] = pk;                         \
    } } while(0)
#define MFMA_PHASE() do {                                                 \
    __builtin_amdgcn_s_setprio(1);                                        \
    _Pragma("unroll")                                                     \
    for (int ks = 0; ks < 2; ++ks) {                                      \
        s16x8 bf[5];                                                      \
        _Pragma("unroll")                                                 \
        for (int ct = 0; ct < 5; ++ct) {                                  \
            const int o = (ct*4 + wid)*16 + l15;                          \
            bf[ct] = *(const s16x8*)(const void*)                         \
                     &ldsW[o*64 + (((ks*4 + q) ^ (o & 7)) << 3)];         \
        }                                                                 \
        _Pragma("unroll")                                                 \
        for (int r = 0; r < 8; ++r) {                                     \
            const int w = r*16 + l15;                                     \
            const s16x8 af = *(const s16x8*)(const void*)                 \
                     &ldsA[w*64 + (((ks*4 + q) ^ (w & 7)) << 3)];         \
            _Pragma("unroll")                                             \
            for (int ct = 0; ct < 5; ++ct)                                \
                acc[r][ct] = MFMA_BF16(af, bf[ct], acc[r][ct], 0, 0, 0);  \
        }                                                                 \
    }                                                                     \
    __builtin_amdgcn_s_setprio(0); } while(0)

    LOAD_A(0);
    STAGE_W(0);
    WRITE_A();
    LOAD_A(1);
    asm volatile("s_waitcnt lgkmcnt(0) vmcnt(32)" ::: "memory");  // W0 + A0-lds done
    __builtin_amdgcn_s_barrier();
    MFMA_PHASE();                            // phase 0
    asm volatile("s_waitcnt lgkmcnt(0)" ::: "memory");
    __builtin_amdgcn_s_barrier();
    STAGE_W(1);
    WRITE_A();                               // A1 -> LDS
    LOAD_A(2);
    asm volatile("s_waitcnt lgkmcnt(0) vmcnt(32)" ::: "memory");  // W1 + A1-lds done
    __builtin_amdgcn_s_barrier();
    MFMA_PHASE();                            // phase 1
    asm volatile("s_waitcnt lgkmcnt(0)" ::: "memory");
    __builtin_amdgcn_s_barrier();
    STAGE_W(2);
    WRITE_A();                               // A2 -> LDS
    asm volatile("s_waitcnt lgkmcnt(0) vmcnt(0)" ::: "memory");   // W2 done
    __builtin_amdgcn_s_barrier();
    MFMA_PHASE();                            // phase 2
    asm volatile("s_waitcnt lgkmcnt(0)" ::: "memory");
    __builtin_amdgcn_s_barrier();

    // ---- epilogue A: Q/K -> LDS image -> full-row 16B stores
    {
        u16* ldsQe = lds;                    // 8192 u16 (16 KB) [w][64c swz]
        u16* ldsKe = lds + 8192;             // 8192 u16
        const int oc = wid*16 + l15;
        #pragma unroll
        for (int r = 0; r < 8; ++r)
            #pragma unroll
            for (int rg = 0; rg < 4; ++rg) {
                const int w = r*16 + q*4 + rg;
                const int idx = w*64 + (((oc >> 3) ^ (w & 7)) << 3) + (oc & 7);
                ldsQe[idx] = f2b(acc[r][0][rg]);
                ldsKe[idx] = f2b(acc[r][1][rg]);
            }
        asm volatile("s_waitcnt lgkmcnt(0)" ::: "memory");
        __builtin_amdgcn_s_barrier();
        #pragma unroll
        for (int i = 0; i < 4; ++i) {
            const int idx = i*256 + t;       // 1024 granules, 32 rows/instr
            const int r = idx >> 3, j = idx & 7;
            const int so = r*64 + ((j ^ (r & 7)) << 3);
            const size_t gb = ((size_t)(b*W_ + r)*H_ + h)*CQK_ + j*8;
            *(s16x8*)(void*)&Qc[gb] = *(const s16x8*)(const void*)&ldsQe[so];
            *(s16x8*)(void*)&Kc[gb] = *(const s16x8*)(const void*)&ldsKe[so];
        }
        asm volatile("s_waitcnt lgkmcnt(0)" ::: "memory");
        __builtin_amdgcn_s_barrier();        // image reads done -> V may overwrite
    }
    // ---- epilogue B: V via LDS transpose
    u16* ldsVe = lds;                        // 24576 u16 (48 KB)
    #pragma unroll
    for (int ct = 2; ct < 5; ++ct) {
        const int c = (ct - 2)*64 + wid*16 + l15;
        #pragma unroll
        for (int r = 0; r < 8; ++r) {
            const int w0 = r*16 + q*4;
            u32x2 pk;
            pk.x = (unsigned)f2b(acc[r][ct][0]) | ((unsigned)f2b(acc[r][ct][1]) << 16);
            pk.y = (unsigned)f2b(acc[r][ct][2]) | ((unsigned)f2b(acc[r][ct][3]) << 16);
            *(u32x2*)(void*)&ldsVe[c*128 + (((w0 >> 3) ^ (c & 7)) << 3) + (w0 & 7)] = pk;
        }
    }
    asm volatile("s_waitcnt lgkmcnt(0)" ::: "memory");
    __builtin_amdgcn_s_barrier();
    #pragma unroll
    for (int i = 0; i < 12; ++i) {
        const int idx = i*256 + t;
        const int c = idx >> 4, j = idx & 15;
        const s16x8 v = *(const s16x8*)(const void*)&ldsVe[c*128 + j*8];
        *(s16x8*)(void*)&Vn[(size_t)(b*C_ + c)*HW_ + h*W_ + ((j ^ (c & 7)) << 3)] = v;
    }
#undef STAGE_W
#undef LOAD_A
#undef WRITE_A
#undef MFMA_PHASE
}

// ------------------------------------------- V transpose: [c][h][w]->[c][w][h]
__global__ __launch_bounds__(256) void ktrv(
    const u16* __restrict__ Vn, u16* __restrict__ Vc)
{
    __shared__ u16 T[128*128];
    const int c = blockIdx.x, b = blockIdx.y;
    const u16* src = Vn + (size_t)(b*C_ + c)*HW_;
    u16*       dst = Vc + (size_t)(b*C_ + c)*HW_;
    const int t = threadIdx.x;
    for (int idx = t; idx < 128*16; idx += 256) {
        const int hh = idx >> 4, o = idx & 15;
        s16x8 v = *(const s16x8*)(void*)(src + hh*128 + o*8);
        *(s16x8*)(void*)(T + hh*128 + ((o ^ (hh & 7)) << 3)) = v;
    }
    __syncthreads();
    const int w = t & 127, half = t >> 7;
    for (int seg = 0; seg < 8; ++seg) {
        const int h0 = half*64 + seg*8;
        s16x8 pk;
        #pragma unroll
        for (int k = 0; k < 8; ++k) {
            const int hh = h0 + k;
            const int chunk = (w >> 3) ^ (hh & 7);
            pk[k] = (short)T[hh*128 + (chunk << 3) + (w & 7)];
        }
        *(s16x8*)(void*)(dst + w*128 + h0) = pk;
    }
}

// ------------- column attention (per b,w): O2 + Mh,Sh [512 thr, 48KB, (512,6)]
__global__ __launch_bounds__(512, 6) void kC(
    const u16* __restrict__ Qc, const u16* __restrict__ Kc,
    const u16* __restrict__ Vc,
    u16* __restrict__ O2, float* __restrict__ Mh, float* __restrict__ Sh)
{
    extern __shared__ char smem[];
    char* ldsK = smem;                       // 16K staging (dies at P)
    char* ldsP = smem;                       // 32K
    char* ldsV = smem + 32768;               // 16K V chunk
    const int w = blockIdx.x, b = blockIdx.y;
    const int t = threadIdx.x, lane = t & 63, wid = t >> 6;
    const int l15 = lane & 15, q = lane >> 4;
    const int arow = (wid << 4) + l15;

    // ---- Q direct to regs (wave-private score rows; linear global layout)
    const u16* qrow = Qc + ((size_t)(b*W_ + w)*H_ + arow)*CQK_;
    s16x8 qf0 = *(const s16x8*)(const void*)(qrow + q*8);
    s16x8 qf1 = *(const s16x8*)(const void*)(qrow + (4 + q)*8);
    // ---- K -> LDS, V chunk0 -> LDS   (vh loads deferred to post-stats:
    //      keeps prologue live-set small for the 85-VGPR (512,6) budget)
    {
        const u16* ksrc = Kc + (size_t)(b*W_ + w)*H_*CQK_;
        for (int idx = t; idx < 1024; idx += 512) {
            const int r = idx >> 3, o = idx & 7;
            *(s16x8*)(ldsK + r*128 + ((o ^ (r & 7)) << 4)) =
                *(const s16x8*)(const void*)(ksrc + idx*8);
        }
    }
    for (int idx = t; idx < 1024; idx += 512) {
        const int lc = idx >> 4, o = idx & 15;
        *(s16x8*)(ldsV + lc*256 + ((o ^ (lc & 7)) << 4)) =
            *(const s16x8*)(const void*)
            (Vc + ((size_t)(b*C_ + lc)*W_ + w)*H_ + o*8);
    }
    __syncthreads();

    // ---- scores: e_h[h][g]
    f32x4 accS[8];
    #pragma unroll
    for (int i = 0; i < 8; ++i) accS[i] = (f32x4){0.f,0.f,0.f,0.f};
    #pragma unroll
    for (int ks = 0; ks < 2; ++ks) {
        const int ch = ks*4 + q;
        const s16x8 af = ks ? qf1 : qf0;
        #pragma unroll
        for (int gt = 0; gt < 8; ++gt) {
            const int br = (gt << 4) + l15;
            s16x8 bf = *(const s16x8*)(ldsK + br*128 + ((ch ^ (br & 7)) << 4));
            accS[gt] = MFMA_BF16(af, bf, accS[gt], 0, 0, 0);
        }
    }
    __syncthreads();                         // K dead -> P region writable

    // ---- diag mask, stats, P (wave-local rows)
    #pragma unroll
    for (int r = 0; r < 4; ++r) {
        const int hh = (wid << 4) + (q << 2) + r;
        #pragma unroll
        for (int gt = 0; gt < 8; ++gt)
            if ((gt << 4) + l15 == hh) accS[gt][r] = -3.0e38f;
        float m = -3.0e38f;
        #pragma unroll
        for (int gt = 0; gt < 8; ++gt) m = fmaxf(m, accS[gt][r]);
        m = fmaxf(m, __shfl_xor(m, 1)); m = fmaxf(m, __shfl_xor(m, 2));
        m = fmaxf(m, __shfl_xor(m, 4)); m = fmaxf(m, __shfl_xor(m, 8));
        float s = 0.f;
        #pragma unroll
        for (int gt = 0; gt < 8; ++gt) {
            const float e = __expf(accS[gt][r] - m);
            s += e;
            const int g = (gt << 4) + l15;
            *(u16*)(ldsP + hh*256 + (((g >> 3) ^ (hh & 7)) << 4) + (g & 7)*2)
                = f2b(e);
        }
        s += __shfl_xor(s, 1); s += __shfl_xor(s, 2);
        s += __shfl_xor(s, 4); s += __shfl_xor(s, 8);
        if (l15 == 0) {
            Mh[(b*W_ + w)*H_ + hh] = m;
            Sh[(b*W_ + w)*H_ + hh] = s;
        }
    }
    // (no barrier: P wave-local, V0 staged since first barrier)

    // ---- V chunk1 into regs NOW (latency hides under PV0 MFMAs)
    s16x8 vh[2];
    #pragma unroll
    for (int i = 0; i < 2; ++i) {
        const int idx = i*512 + t;
        const int c = 64 + (idx >> 4), o = idx & 15;
        vh[i] = *(const s16x8*)(const void*)
                (Vc + ((size_t)(b*C_ + c)*W_ + w)*H_ + o*8);
    }

#define KC_PV(accv) do {                                                  \
    _Pragma("unroll")                                                     \
    for (int ks = 0; ks < 4; ++ks) {                                      \
        const int ch = ks*4 + q;                                          \
        s16x8 afp = *(const s16x8*)(ldsP + arow*256 + ((ch ^ (arow & 7)) << 4)); \
        _Pragma("unroll")                                                 \
        for (int ct = 0; ct < 4; ++ct) {                                  \
            const int vr = (ct << 4) + l15;                               \
            s16x8 bfv = *(const s16x8*)(ldsV + vr*256 + ((ch ^ (vr & 7)) << 4)); \
            accv[ct] = MFMA_BF16(afp, bfv, accv[ct], 0, 0, 0);            \
        }                                                                 \
    } } while(0)
#define KC_O2W(accv, cb) do {                                             \
    _Pragma("unroll")                                                     \
    for (int ct = 0; ct < 4; ++ct) {                                      \
        const int c = (cb) + (ct << 4) + l15;                             \
        _Pragma("unroll")                                                 \
        for (int r = 0; r < 4; ++r) {                                     \
            const int hh = (wid << 4) + (q << 2) + r;                     \
            O2[((size_t)(b*H_ + hh)*W_ + w)*C_ + c] = f2b(accv[ct][r]);   \
        }                                                                 \
    } } while(0)

    f32x4 accO[4];
    #pragma unroll
    for (int i = 0; i < 4; ++i) accO[i] = (f32x4){0.f,0.f,0.f,0.f};
    KC_PV(accO);                             // chunk0 (c 0..63)
    __syncthreads();                         // V0 reads done
    #pragma unroll
    for (int i = 0; i < 2; ++i) {            // dsw V1; reload vh <- V2
        const int idx = i*512 + t;
        const int lc = idx >> 4, o = idx & 15;
        *(s16x8*)(ldsV + lc*256 + ((o ^ (lc & 7)) << 4)) = vh[i];
    }
    #pragma unroll
    for (int i = 0; i < 2; ++i) {
        const int idx = i*512 + t;
        const int c = 128 + (idx >> 4), o = idx & 15;
        vh[i] = *(const s16x8*)(const void*)
                (Vc + ((size_t)(b*C_ + c)*W_ + w)*H_ + o*8);
    }
    __syncthreads();                         // V1 visible
    KC_O2W(accO, 0);
    #pragma unroll
    for (int i = 0; i < 4; ++i) accO[i] = (f32x4){0.f,0.f,0.f,0.f};
    KC_PV(accO);                             // chunk1 (c 64..127)
    __syncthreads();                         // V1 reads done
    #pragma unroll
    for (int i = 0; i < 2; ++i) {            // dsw V2
        const int idx = i*512 + t;
        const int lc = idx >> 4, o = idx & 15;
        *(s16x8*)(ldsV + lc*256 + ((o ^ (lc & 7)) << 4)) = vh[i];
    }
    __syncthreads();                         // V2 visible
    KC_O2W(accO, 64);
    #pragma unroll
    for (int i = 0; i < 4; ++i) accO[i] = (f32x4){0.f,0.f,0.f,0.f};
    KC_PV(accO);                             // chunk2 (c 128..191)
    KC_O2W(accO, 128);
#undef KC_PV
#undef KC_O2W
}

// ---- row attention + fused final (per b,h) [512 thr, 49KB LDS, (512,6)]
__global__ __launch_bounds__(512, 6) void kR(
    const u16* __restrict__ Qc, const u16* __restrict__ Kc,
    const u16* __restrict__ Vn, const u16* __restrict__ O2,
    const float* __restrict__ Mh, const float* __restrict__ Sh,
    const float* __restrict__ x, const float* __restrict__ gamma,
    float* __restrict__ out)
{
    extern __shared__ char smem[];
    char*  ldsK  = smem;                     // 16K staging (dies at P)
    char*  ldsP  = smem;                     // 32K
    char*  ldsV  = smem + 32768;             // 16K V chunk
    float* sScw  = (float*)(smem + 49152);   // 512B
    float* sSch  = (float*)(smem + 49664);   // 512B
    const int h = blockIdx.x, b = blockIdx.y;
    const int t = threadIdx.x, lane = t & 63, wid = t >> 6;
    const int l15 = lane & 15, q = lane >> 4;
    const int arow = (wid << 4) + l15;       // score row / P row (w)
    const int wbase = (wid << 4) + (q << 2); // this thread's 4 w's (D rows)
    const float gam = gamma[0];

    // ---- Q direct to regs
    const u16* qrow = Qc + ((size_t)(b*W_ + arow)*H_ + h)*CQK_;
    s16x8 qf0 = *(const s16x8*)(const void*)(qrow + q*8);
    s16x8 qf1 = *(const s16x8*)(const void*)(qrow + (4 + q)*8);
    // ---- K -> LDS, V chunk0 -> LDS   (vh deferred to post-stats)
    for (int idx = t; idx < 1024; idx += 512) {
        const int r = idx >> 3, o = idx & 7;
        *(s16x8*)(ldsK + r*128 + ((o ^ (r & 7)) << 4)) =
            *(const s16x8*)(const void*)
            (Kc + ((size_t)(b*W_ + r)*H_ + h)*CQK_ + o*8);
    }
    for (int idx = t; idx < 1024; idx += 512) {
        const int lc = idx >> 4, o = idx & 15;
        *(s16x8*)(ldsV + lc*256 + ((o ^ (lc & 7)) << 4)) =
            *(const s16x8*)(const void*)
            (Vn + (size_t)(b*C_ + lc)*HW_ + h*W_ + o*8);
    }
    __syncthreads();

    // ---- scores: e_w[w][v]
    f32x4 accS[8];
    #pragma unroll
    for (int i = 0; i < 8; ++i) accS[i] = (f32x4){0.f,0.f,0.f,0.f};
    #pragma unroll
    for (int ks = 0; ks < 2; ++ks) {
        const int ch = ks*4 + q;
        const s16x8 af = ks ? qf1 : qf0;
        #pragma unroll
        for (int vt = 0; vt < 8; ++vt) {
            const int br = (vt << 4) + l15;
            s16x8 bf = *(const s16x8*)(ldsK + br*128 + ((ch ^ (br & 7)) << 4));
            accS[vt] = MFMA_BF16(af, bf, accS[vt], 0, 0, 0);
        }
    }
    __syncthreads();                         // K dead -> P region writable

    // ---- stats, P (wave-local), merged scales (l15==0 lanes, wave-local)
    #pragma unroll
    for (int r = 0; r < 4; ++r) {
        const int ww = (wid << 4) + (q << 2) + r;
        float m = -3.0e38f;
        #pragma unroll
        for (int vt = 0; vt < 8; ++vt) m = fmaxf(m, accS[vt][r]);
        m = fmaxf(m, __shfl_xor(m, 1)); m = fmaxf(m, __shfl_xor(m, 2));
        m = fmaxf(m, __shfl_xor(m, 4)); m = fmaxf(m, __shfl_xor(m, 8));
        float s = 0.f;
        #pragma unroll
        for (int vt = 0; vt < 8; ++vt) {
            const float e = __expf(accS[vt][r] - m);
            s += e;
            const int v = (vt << 4) + l15;
            *(u16*)(ldsP + ww*256 + (((v >> 3) ^ (ww & 7)) << 4) + (v & 7)*2)
                = f2b(e);
        }
        s += __shfl_xor(s, 1); s += __shfl_xor(s, 2);
        s += __shfl_xor(s, 4); s += __shfl_xor(s, 8);
        if (l15 == 0) {                      // merge with column stats
            const float mh  = Mh[(b*W_ + ww)*H_ + h];
            const float shv = Sh[(b*W_ + ww)*H_ + h];
            const float M = fmaxf(mh, m);
            const float S = shv*__expf(mh - M) + s*__expf(m - M);
            sScw[ww] = __expf(m - M) / S;
            sSch[ww] = __expf(mh - M) / S;
        }
    }
    // (no barrier: P + scales wave-local; V0 ready since first barrier)
    float scw[4], sch[4];
    #pragma unroll
    for (int r = 0; r < 4; ++r) { scw[r] = sScw[wbase + r]; sch[r] = sSch[wbase + r]; }

    // ---- V chunk1 into regs NOW (latency hides under PV0 MFMAs)
    s16x8 vh[2];
    #pragma unroll
    for (int i = 0; i < 2; ++i) {
        const int idx = i*512 + t;
        const int c = 64 + (idx >> 4), o = idx & 15;
        vh[i] = *(const s16x8*)(const void*)
                (Vn + (size_t)(b*C_ + c)*HW_ + h*W_ + o*8);
    }

    const u16* o2p = O2 + (size_t)(b*H_ + h)*W_*C_;

#define KR_PV(accv) do {                                                  \
    _Pragma("unroll")                                                     \
    for (int ks = 0; ks < 4; ++ks) {                                      \
        const int ch = ks*4 + q;                                          \
        s16x8 afp = *(const s16x8*)(ldsP + arow*256 + ((ch ^ (arow & 7)) << 4)); \
        _Pragma("unroll")                                                 \
        for (int ct = 0; ct < 4; ++ct) {                                  \
            const int vr = (ct << 4) + l15;                               \
            s16x8 bfv = *(const s16x8*)(ldsV + vr*256 + ((ch ^ (vr & 7)) << 4)); \
            accv[ct] = MFMA_BF16(afp, bfv, accv[ct], 0, 0, 0);            \
        }                                                                 \
    } } while(0)
// direct-read epilogue (no persistent prefetch arrays: VGPR discipline)
#define KR_EPI(k, accv) do {                                              \
    _Pragma("unroll")                                                     \
    for (int ct = 0; ct < 4; ++ct) {                                      \
        const int c = (k)*64 + (ct << 4) + l15;                           \
        const size_t ga = (size_t)(b*C_ + c)*HW_ + h*W_ + wbase;          \
        const f32x4 xv = *(const f32x4*)(const void*)(x + ga);            \
        f32x4 res;                                                        \
        _Pragma("unroll")                                                 \
        for (int r = 0; r < 4; ++r) {                                     \
            const float o2 = b2f(o2p[(size_t)(wbase + r)*C_ + c]);        \
            res[r] = gam*(accv[ct][r]*scw[r] + o2*sch[r]) + xv[r];        \
        }                                                                 \
        *(f32x4*)(void*)(out + ga) = res;                                 \
    } } while(0)

    f32x4 accO[4];
    #pragma unroll
    for (int i = 0; i < 4; ++i) accO[i] = (f32x4){0.f,0.f,0.f,0.f};
    KR_PV(accO);                             // chunk0 (c 0..63)
    __syncthreads();                         // V0 reads done
    #pragma unroll
    for (int i = 0; i < 2; ++i) {            // dsw V1; reload vh <- V2
        const int idx = i*512 + t;
        const int lc = idx >> 4, o = idx & 15;
        *(s16x8*)(ldsV + lc*256 + ((o ^ (lc & 7)) << 4)) = vh[i];
    }
    #pragma unroll
    for (int i = 0; i < 2; ++i) {
        const int idx = i*512 + t;
        const int c = 128 + (idx >> 4), o = idx & 15;
        vh[i] = *(const s16x8*)(const void*)
                (Vn + (size_t)(b*C_ + c)*HW_ + h*W_ + o*8);
    }
    KR_EPI(0, accO);                         // stores cover dsw drain
    __syncthreads();                         // V1 visible
    #pragma unroll
    for (int i = 0; i < 4; ++i) accO[i] = (f32x4){0.f,0.f,0.f,0.f};
    KR_PV(accO);                             // chunk1 (c 64..127)
    __syncthreads();                         // V1 reads done
    #pragma unroll
    for (int i = 0; i < 2; ++i) {            // dsw V2
        const int idx = i*512 + t;
        const int lc = idx >> 4, o = idx & 15;
        *(s16x8*)(ldsV + lc*256 + ((o ^ (lc & 7)) << 4)) = vh[i];
    }
    KR_EPI(1, accO);
    __syncthreads();                         // V2 visible
    #pragma unroll
    for (int i = 0; i < 4; ++i) accO[i] = (f32x4){0.f,0.f,0.f,0.f};
    KR_PV(accO);                             // chunk2 (c 128..191)
    KR_EPI(2, accO);
#undef KR_PV
#undef KR_EPI
}

extern "C" void kernel_launch(void* const* d_in, const int* in_sizes, int n_in,
                              void* d_out, int out_size, void* d_ws, size_t ws_size,
                              hipStream_t stream)
{
    const float* x  = (const float*)d_in[0];
    const float* Wq = (const float*)d_in[1];
    const float* bq = (const float*)d_in[2];
    const float* Wk = (const float*)d_in[3];
    const float* bk = (const float*)d_in[4];
    const float* Wv = (const float*)d_in[5];
    const float* bv = (const float*)d_in[6];
    const float* gm = (const float*)d_in[7];
    float* out = (float*)d_out;

    u16* Qc = (u16*)d_ws;
    u16* Kc = Qc + 8388608;
    u16* Vn = Kc + 8388608;
    u16* Vc = Vn + 25165824;
    u16* O2 = Vc + 25165824;                 // 25165824 u16
    float* Mh = (float*)(O2 + 25165824);
    float* Sh = Mh + 131072;
    u16*  Wb = (u16*)(Sh + 131072);          // 61440 u16
    float* Bb = (float*)(Wb + 61440);        // 320 f32

    hipLaunchKernelGGL(kwcast, dim3(320), dim3(256), 0, stream,
                       Wq, bq, Wk, bk, Wv, bv, Wb, Bb);
    hipLaunchKernelGGL(kprojM, dim3(H_, B_), dim3(256), 0, stream,
                       x, Wb, Bb, Qc, Kc, Vn);
    hipLaunchKernelGGL(ktrv, dim3(C_, B_), dim3(256), 0, stream, Vn, Vc);
    hipLaunchKernelGGL(kC, dim3(W_, B_), dim3(512), 49152, stream,
                       Qc, Kc, Vc, O2, Mh, Sh);
    hipLaunchKernelGGL(kR, dim3(H_, B_), dim3(512), 50176, stream,
                       Qc, Kc, Vn, O2, Mh, Sh, x, gm, out);
}

// Round 12
// 170.476 us; speedup vs baseline: 1.5240x; 1.0627x over previous
//
#include <hip/hip_runtime.h>
#include <math.h>

// RCC criss-cross attention, MFMA-bf16 pipeline. B=8, C=192, CQK=64, H=W=128.
//
//  kwcast : Wq|Wk|Wv fp32 -> Wb bf16 pre-swizzled per-phase LDS image; bias
//  kprojM : fused GEMM reading x fp32 directly; A DOUBLE-BUFFERED (r12):
//           WRITE_A(p+1) overlaps MFMA(p); Q/K epilogue via LDS transpose
//  ktrv   : V transpose -> Vc [b][c][w][h]      (at 100MB traffic floor)
//  kC     : per (b,w): e_h MFMA (diag) -> Mh,Sh; P -> PV MFMA -> O2 [b][h][w][c]
//  kR     : per (b,h): e_w MFMA -> merged scales; PV in 3 V-chunks; fused final
//
// kR/kC CLOSED (r9-r11): 73us invariant across occupancy 33-44%, prefetch
// depth, V-chunking -> streaming wall (~4.6 TB/s logical, zero inter-block
// reuse). Register discipline: (512,6) spills; vh deferred post-stats;
// direct-read epilogue.

#define B_   8
#define C_   192
#define CQK_ 64
#define H_   128
#define W_   128
#define HW_  (H_*W_)

typedef unsigned short u16;
typedef __attribute__((ext_vector_type(8))) short    s16x8;
typedef __attribute__((ext_vector_type(4))) float    f32x4;
typedef __attribute__((ext_vector_type(2))) unsigned u32x2;
#define MFMA_BF16 __builtin_amdgcn_mfma_f32_16x16x32_bf16

__device__ __forceinline__ u16 f2b(float f) {
    unsigned u = __float_as_uint(f);
    return (u16)((u + 0x7fffu + ((u >> 16) & 1u)) >> 16);   // RNE
}
__device__ __forceinline__ float b2f(u16 v) {
    return __uint_as_float(((unsigned)v) << 16);
}
// raw global->LDS 16B/lane: LDS dest = m0 + lane*16 (wave-uniform m0)
__device__ __forceinline__ void gll16(const u16* gsrc, unsigned lds_byte) {
    asm volatile("s_mov_b32 m0, %1\n\t"
                 "global_load_lds_dwordx4 %0, off"
                 :: "v"(gsrc), "s"(lds_byte) : "memory");
}

// ------------------------------------------------ W -> bf16 pre-swizzled + bias
__global__ __launch_bounds__(256) void kwcast(
    const float* __restrict__ Wq, const float* __restrict__ bq,
    const float* __restrict__ Wk, const float* __restrict__ bk,
    const float* __restrict__ Wv, const float* __restrict__ bv,
    u16* __restrict__ Wb, float* __restrict__ Bb)
{
    const int o = blockIdx.x;                // 320 rows
    const float *row, *bias; int oo;
    if (o < 64)        { row = Wq; bias = bq; oo = o;       }
    else if (o < 128)  { row = Wk; bias = bk; oo = o - 64;  }
    else               { row = Wv; bias = bv; oo = o - 128; }
    const int t = threadIdx.x;
    if (t < C_) {
        const int p = t >> 6, cc = t & 63;
        Wb[p*20480 + o*64 + (((cc >> 3) ^ (o & 7)) << 3) + (cc & 7)]
            = f2b(row[oo*C_ + t]);
    }
    if (t == C_) Bb[o] = bias[oo];
}

// ------------------- fused MFMA projection GEMM (reads x fp32 directly)
// LDS u16 idx: A buf0 [0,8192), A buf1 [8192,16384), ldsW [16384,36864).
// Epilogue: Q/K images in [0,16384); V image in [0,24576).
__global__ __launch_bounds__(256, 2) void kprojM(
    const float* __restrict__ x,
    const u16* __restrict__ Wb, const float* __restrict__ Bb,
    u16* __restrict__ Qc, u16* __restrict__ Kc, u16* __restrict__ Vn)
{
    __shared__ u16 lds[36864];               // 72 KB
    u16* ldsW = lds + 16384;
    const int h = blockIdx.x, b = blockIdx.y;
    const int t = threadIdx.x, lane = t & 63, wid = t >> 6;
    const int l15 = lane & 15, q = lane >> 4;
    const float* xb = x + (size_t)b*C_*HW_ + h*W_;
    const int wql = t & 127, cpair = (t >> 7) << 1;

    f32x4 acc[8][5];
    #pragma unroll
    for (int ct = 0; ct < 5; ++ct) {
        const float bv = Bb[(ct*4 + wid)*16 + l15];
        #pragma unroll
        for (int r = 0; r < 8; ++r) acc[r][ct] = (f32x4){bv, bv, bv, bv};
    }

    const unsigned wofs = __builtin_amdgcn_readfirstlane(32768u + (unsigned)wid*1024u);
    float va0[16], va1[16];                  // single reg staging set (reused)

#define STAGE_W(p) do {                                                   \
    const u16* g = Wb + (p)*20480 + wid*512 + lane*8;                     \
    _Pragma("unroll")                                                     \
    for (int i = 0; i < 10; ++i) gll16(g + i*2048, wofs + i*4096); } while(0)
#define LOAD_A(p) do {                                                    \
    _Pragma("unroll")                                                     \
    for (int i = 0; i < 16; ++i) {                                        \
        const int c = i*4 + cpair;                                        \
        va0[i] = xb[(size_t)((p)*64 + c    )*HW_ + wql];                  \
        va1[i] = xb[(size_t)((p)*64 + c + 1)*HW_ + wql];                  \
    } } while(0)
#define WRITE_A(buf) do {                                                 \
    u16* ldsA = lds + (buf)*8192;                                         \
    _Pragma("unroll")                                                     \
    for (int i = 0; i < 16; ++i) {                                        \
        const int c = i*4 + cpair;                                        \
        const unsigned pk = (unsigned)f2b(va0[i]) | ((unsigned)f2b(va1[i]) << 16); \
        *(unsigned*)(void*)&ldsA[wql*64 + (((c >> 3) ^ (wql & 7)) << 3)   \
                                 + (c & 7)] = pk;                         \
    } } while(0)
#define MFMA_PHASE(buf) do {                                              \
    const u16* bA = lds + (buf)*8192;                                     \
    __builtin_amdgcn_s_setprio(1);                                        \
    _Pragma("unroll")                                                     \
    for (int ks = 0; ks < 2; ++ks) {                                      \
        s16x8 bf[5];                                                      \
        _Pragma("unroll")                                                 \
        for (int ct = 0; ct < 5; ++ct) {                                  \
            const int o = (ct*4 + wid)*16 + l15;                          \
            bf[ct] = *(const s16x8*)(const void*)                         \
                     &ldsW[o*64 + (((ks*4 + q) ^ (o & 7)) << 3)];         \
        }                                                                 \
        _Pragma("unroll")                                                 \
        for (int r = 0; r < 8; ++r) {                                     \
            const int w = r*16 + l15;                                     \
            const s16x8 af = *(const s16x8*)(const void*)                 \
                     &bA[w*64 + (((ks*4 + q) ^ (w & 7)) << 3)];           \
            _Pragma("unroll")                                             \
            for (int ct = 0; ct < 5; ++ct)                                \
                acc[r][ct] = MFMA_BF16(af, bf[ct], acc[r][ct], 0, 0, 0);  \
        }                                                                 \
    }                                                                     \
    __builtin_amdgcn_s_setprio(0); } while(0)

    // prologue
    LOAD_A(0);
    STAGE_W(0);
    WRITE_A(0);                              // waits A0 loads; glls keep flying
    LOAD_A(1);
    asm volatile("s_waitcnt vmcnt(32) lgkmcnt(0)" ::: "memory");  // W0 landed, b0 visible
    __builtin_amdgcn_s_barrier();
    // phase 0: A1-write overlaps MFMA(b0)
    WRITE_A(1);
    MFMA_PHASE(0);
    asm volatile("s_waitcnt lgkmcnt(0)" ::: "memory");            // b1 visible
    __builtin_amdgcn_s_barrier();
    STAGE_W(1);
    LOAD_A(2);
    asm volatile("s_waitcnt vmcnt(32)" ::: "memory");             // W1 landed
    __builtin_amdgcn_s_barrier();
    // phase 1: A2-write overlaps MFMA(b1)
    WRITE_A(0);
    MFMA_PHASE(1);
    asm volatile("s_waitcnt lgkmcnt(0)" ::: "memory");            // b0 visible
    __builtin_amdgcn_s_barrier();
    STAGE_W(2);
    asm volatile("s_waitcnt vmcnt(0)" ::: "memory");              // W2 landed
    __builtin_amdgcn_s_barrier();
    // phase 2
    MFMA_PHASE(0);
    asm volatile("s_waitcnt lgkmcnt(0)" ::: "memory");
    __builtin_amdgcn_s_barrier();

    // ---- epilogue A: Q/K -> LDS image -> full-row 16B stores
    {
        u16* ldsQe = lds;                    // 8192 u16 (16 KB) [w][64c swz]
        u16* ldsKe = lds + 8192;             // 8192 u16
        const int oc = wid*16 + l15;
        #pragma unroll
        for (int r = 0; r < 8; ++r)
            #pragma unroll
            for (int rg = 0; rg < 4; ++rg) {
                const int w = r*16 + q*4 + rg;
                const int idx = w*64 + (((oc >> 3) ^ (w & 7)) << 3) + (oc & 7);
                ldsQe[idx] = f2b(acc[r][0][rg]);
                ldsKe[idx] = f2b(acc[r][1][rg]);
            }
        asm volatile("s_waitcnt lgkmcnt(0)" ::: "memory");
        __builtin_amdgcn_s_barrier();
        #pragma unroll
        for (int i = 0; i < 4; ++i) {
            const int idx = i*256 + t;       // 1024 granules, 32 rows/instr
            const int r = idx >> 3, j = idx & 7;
            const int so = r*64 + ((j ^ (r & 7)) << 3);
            const size_t gb = ((size_t)(b*W_ + r)*H_ + h)*CQK_ + j*8;
            *(s16x8*)(void*)&Qc[gb] = *(const s16x8*)(const void*)&ldsQe[so];
            *(s16x8*)(void*)&Kc[gb] = *(const s16x8*)(const void*)&ldsKe[so];
        }
        asm volatile("s_waitcnt lgkmcnt(0)" ::: "memory");
        __builtin_amdgcn_s_barrier();        // image reads done -> V may overwrite
    }
    // ---- epilogue B: V via LDS transpose
    u16* ldsVe = lds;                        // 24576 u16 (48 KB)
    #pragma unroll
    for (int ct = 2; ct < 5; ++ct) {
        const int c = (ct - 2)*64 + wid*16 + l15;
        #pragma unroll
        for (int r = 0; r < 8; ++r) {
            const int w0 = r*16 + q*4;
            u32x2 pk;
            pk.x = (unsigned)f2b(acc[r][ct][0]) | ((unsigned)f2b(acc[r][ct][1]) << 16);
            pk.y = (unsigned)f2b(acc[r][ct][2]) | ((unsigned)f2b(acc[r][ct][3]) << 16);
            *(u32x2*)(void*)&ldsVe[c*128 + (((w0 >> 3) ^ (c & 7)) << 3) + (w0 & 7)] = pk;
        }
    }
    asm volatile("s_waitcnt lgkmcnt(0)" ::: "memory");
    __builtin_amdgcn_s_barrier();
    #pragma unroll
    for (int i = 0; i < 12; ++i) {
        const int idx = i*256 + t;
        const int c = idx >> 4, j = idx & 15;
        const s16x8 v = *(const s16x8*)(const void*)&ldsVe[c*128 + j*8];
        *(s16x8*)(void*)&Vn[(size_t)(b*C_ + c)*HW_ + h*W_ + ((j ^ (c & 7)) << 3)] = v;
    }
#undef STAGE_W
#undef LOAD_A
#undef WRITE_A
#undef MFMA_PHASE
}

// ------------------------------------------- V transpose: [c][h][w]->[c][w][h]
__global__ __launch_bounds__(256) void ktrv(
    const u16* __restrict__ Vn, u16* __restrict__ Vc)
{
    __shared__ u16 T[128*128];
    const int c = blockIdx.x, b = blockIdx.y;
    const u16* src = Vn + (size_t)(b*C_ + c)*HW_;
    u16*       dst = Vc + (size_t)(b*C_ + c)*HW_;
    const int t = threadIdx.x;
    for (int idx = t; idx < 128*16; idx += 256) {
        const int hh = idx >> 4, o = idx & 15;
        s16x8 v = *(const s16x8*)(void*)(src + hh*128 + o*8);
        *(s16x8*)(void*)(T + hh*128 + ((o ^ (hh & 7)) << 3)) = v;
    }
    __syncthreads();
    const int w = t & 127, half = t >> 7;
    for (int seg = 0; seg < 8; ++seg) {
        const int h0 = half*64 + seg*8;
        s16x8 pk;
        #pragma unroll
        for (int k = 0; k < 8; ++k) {
            const int hh = h0 + k;
            const int chunk = (w >> 3) ^ (hh & 7);
            pk[k] = (short)T[hh*128 + (chunk << 3) + (w & 7)];
        }
        *(s16x8*)(void*)(dst + w*128 + h0) = pk;
    }
}

// ------------- column attention (per b,w): O2 + Mh,Sh [512 thr, 48KB, (512,6)]
__global__ __launch_bounds__(512, 6) void kC(
    const u16* __restrict__ Qc, const u16* __restrict__ Kc,
    const u16* __restrict__ Vc,
    u16* __restrict__ O2, float* __restrict__ Mh, float* __restrict__ Sh)
{
    extern __shared__ char smem[];
    char* ldsK = smem;                       // 16K staging (dies at P)
    char* ldsP = smem;                       // 32K
    char* ldsV = smem + 32768;               // 16K V chunk
    const int w = blockIdx.x, b = blockIdx.y;
    const int t = threadIdx.x, lane = t & 63, wid = t >> 6;
    const int l15 = lane & 15, q = lane >> 4;
    const int arow = (wid << 4) + l15;

    // ---- Q direct to regs (wave-private score rows; linear global layout)
    const u16* qrow = Qc + ((size_t)(b*W_ + w)*H_ + arow)*CQK_;
    s16x8 qf0 = *(const s16x8*)(const void*)(qrow + q*8);
    s16x8 qf1 = *(const s16x8*)(const void*)(qrow + (4 + q)*8);
    // ---- K -> LDS, V chunk0 -> LDS   (vh loads deferred to post-stats)
    {
        const u16* ksrc = Kc + (size_t)(b*W_ + w)*H_*CQK_;
        for (int idx = t; idx < 1024; idx += 512) {
            const int r = idx >> 3, o = idx & 7;
            *(s16x8*)(ldsK + r*128 + ((o ^ (r & 7)) << 4)) =
                *(const s16x8*)(const void*)(ksrc + idx*8);
        }
    }
    for (int idx = t; idx < 1024; idx += 512) {
        const int lc = idx >> 4, o = idx & 15;
        *(s16x8*)(ldsV + lc*256 + ((o ^ (lc & 7)) << 4)) =
            *(const s16x8*)(const void*)
            (Vc + ((size_t)(b*C_ + lc)*W_ + w)*H_ + o*8);
    }
    __syncthreads();

    // ---- scores: e_h[h][g]
    f32x4 accS[8];
    #pragma unroll
    for (int i = 0; i < 8; ++i) accS[i] = (f32x4){0.f,0.f,0.f,0.f};
    #pragma unroll
    for (int ks = 0; ks < 2; ++ks) {
        const int ch = ks*4 + q;
        const s16x8 af = ks ? qf1 : qf0;
        #pragma unroll
        for (int gt = 0; gt < 8; ++gt) {
            const int br = (gt << 4) + l15;
            s16x8 bf = *(const s16x8*)(ldsK + br*128 + ((ch ^ (br & 7)) << 4));
            accS[gt] = MFMA_BF16(af, bf, accS[gt], 0, 0, 0);
        }
    }
    __syncthreads();                         // K dead -> P region writable

    // ---- diag mask, stats, P (wave-local rows)
    #pragma unroll
    for (int r = 0; r < 4; ++r) {
        const int hh = (wid << 4) + (q << 2) + r;
        #pragma unroll
        for (int gt = 0; gt < 8; ++gt)
            if ((gt << 4) + l15 == hh) accS[gt][r] = -3.0e38f;
        float m = -3.0e38f;
        #pragma unroll
        for (int gt = 0; gt < 8; ++gt) m = fmaxf(m, accS[gt][r]);
        m = fmaxf(m, __shfl_xor(m, 1)); m = fmaxf(m, __shfl_xor(m, 2));
        m = fmaxf(m, __shfl_xor(m, 4)); m = fmaxf(m, __shfl_xor(m, 8));
        float s = 0.f;
        #pragma unroll
        for (int gt = 0; gt < 8; ++gt) {
            const float e = __expf(accS[gt][r] - m);
            s += e;
            const int g = (gt << 4) + l15;
            *(u16*)(ldsP + hh*256 + (((g >> 3) ^ (hh & 7)) << 4) + (g & 7)*2)
                = f2b(e);
        }
        s += __shfl_xor(s, 1); s += __shfl_xor(s, 2);
        s += __shfl_xor(s, 4); s += __shfl_xor(s, 8);
        if (l15 == 0) {
            Mh[(b*W_ + w)*H_ + hh] = m;
            Sh[(b*W_ + w)*H_ + hh] = s;
        }
    }
    // (no barrier: P wave-local, V0 staged since first barrier)

    // ---- V chunk1 into regs NOW (latency hides under PV0 MFMAs)
    s16x8 vh[2];
    #pragma unroll
    for (int i = 0; i < 2; ++i) {
        const int idx = i*512 + t;
        const int c = 64 + (idx >> 4), o = idx & 15;
        vh[i] = *(const s16x8*)(const void*)
                (Vc + ((size_t)(b*C_ + c)*W_ + w)*H_ + o*8);
    }

#define KC_PV(accv) do {                                                  \
    _Pragma("unroll")                                                     \
    for (int ks = 0; ks < 4; ++ks) {                                      \
        const int ch = ks*4 + q;                                          \
        s16x8 afp = *(const s16x8*)(ldsP + arow*256 + ((ch ^ (arow & 7)) << 4)); \
        _Pragma("unroll")                                                 \
        for (int ct = 0; ct < 4; ++ct) {                                  \
            const int vr = (ct << 4) + l15;                               \
            s16x8 bfv = *(const s16x8*)(ldsV + vr*256 + ((ch ^ (vr & 7)) << 4)); \
            accv[ct] = MFMA_BF16(afp, bfv, accv[ct], 0, 0, 0);            \
        }                                                                 \
    } } while(0)
#define KC_O2W(accv, cb) do {                                             \
    _Pragma("unroll")                                                     \
    for (int ct = 0; ct < 4; ++ct) {                                      \
        const int c = (cb) + (ct << 4) + l15;                             \
        _Pragma("unroll")                                                 \
        for (int r = 0; r < 4; ++r) {                                     \
            const int hh = (wid << 4) + (q << 2) + r;                     \
            O2[((size_t)(b*H_ + hh)*W_ + w)*C_ + c] = f2b(accv[ct][r]);   \
        }                                                                 \
    } } while(0)

    f32x4 accO[4];
    #pragma unroll
    for (int i = 0; i < 4; ++i) accO[i] = (f32x4){0.f,0.f,0.f,0.f};
    KC_PV(accO);                             // chunk0 (c 0..63)
    __syncthreads();                         // V0 reads done
    #pragma unroll
    for (int i = 0; i < 2; ++i) {            // dsw V1; reload vh <- V2
        const int idx = i*512 + t;
        const int lc = idx >> 4, o = idx & 15;
        *(s16x8*)(ldsV + lc*256 + ((o ^ (lc & 7)) << 4)) = vh[i];
    }
    #pragma unroll
    for (int i = 0; i < 2; ++i) {
        const int idx = i*512 + t;
        const int c = 128 + (idx >> 4), o = idx & 15;
        vh[i] = *(const s16x8*)(const void*)
                (Vc + ((size_t)(b*C_ + c)*W_ + w)*H_ + o*8);
    }
    __syncthreads();                         // V1 visible
    KC_O2W(accO, 0);
    #pragma unroll
    for (int i = 0; i < 4; ++i) accO[i] = (f32x4){0.f,0.f,0.f,0.f};
    KC_PV(accO);                             // chunk1 (c 64..127)
    __syncthreads();                         // V1 reads done
    #pragma unroll
    for (int i = 0; i < 2; ++i) {            // dsw V2
        const int idx = i*512 + t;
        const int lc = idx >> 4, o = idx & 15;
        *(s16x8*)(ldsV + lc*256 + ((o ^ (lc & 7)) << 4)) = vh[i];
    }
    __syncthreads();                         // V2 visible
    KC_O2W(accO, 64);
    #pragma unroll
    for (int i = 0; i < 4; ++i) accO[i] = (f32x4){0.f,0.f,0.f,0.f};
    KC_PV(accO);                             // chunk2 (c 128..191)
    KC_O2W(accO, 128);
#undef KC_PV
#undef KC_O2W
}

// ---- row attention + fused final (per b,h) [512 thr, 49KB LDS, (512,6)]
__global__ __launch_bounds__(512, 6) void kR(
    const u16* __restrict__ Qc, const u16* __restrict__ Kc,
    const u16* __restrict__ Vn, const u16* __restrict__ O2,
    const float* __restrict__ Mh, const float* __restrict__ Sh,
    const float* __restrict__ x, const float* __restrict__ gamma,
    float* __restrict__ out)
{
    extern __shared__ char smem[];
    char*  ldsK  = smem;                     // 16K staging (dies at P)
    char*  ldsP  = smem;                     // 32K
    char*  ldsV  = smem + 32768;             // 16K V chunk
    float* sScw  = (float*)(smem + 49152);   // 512B
    float* sSch  = (float*)(smem + 49664);   // 512B
    const int h = blockIdx.x, b = blockIdx.y;
    const int t = threadIdx.x, lane = t & 63, wid = t >> 6;
    const int l15 = lane & 15, q = lane >> 4;
    const int arow = (wid << 4) + l15;       // score row / P row (w)
    const int wbase = (wid << 4) + (q << 2); // this thread's 4 w's (D rows)
    const float gam = gamma[0];

    // ---- Q direct to regs
    const u16* qrow = Qc + ((size_t)(b*W_ + arow)*H_ + h)*CQK_;
    s16x8 qf0 = *(const s16x8*)(const void*)(qrow + q*8);
    s16x8 qf1 = *(const s16x8*)(const void*)(qrow + (4 + q)*8);
    // ---- K -> LDS, V chunk0 -> LDS   (vh deferred to post-stats)
    for (int idx = t; idx < 1024; idx += 512) {
        const int r = idx >> 3, o = idx & 7;
        *(s16x8*)(ldsK + r*128 + ((o ^ (r & 7)) << 4)) =
            *(const s16x8*)(const void*)
            (Kc + ((size_t)(b*W_ + r)*H_ + h)*CQK_ + o*8);
    }
    for (int idx = t; idx < 1024; idx += 512) {
        const int lc = idx >> 4, o = idx & 15;
        *(s16x8*)(ldsV + lc*256 + ((o ^ (lc & 7)) << 4)) =
            *(const s16x8*)(const void*)
            (Vn + (size_t)(b*C_ + lc)*HW_ + h*W_ + o*8);
    }
    __syncthreads();

    // ---- scores: e_w[w][v]
    f32x4 accS[8];
    #pragma unroll
    for (int i = 0; i < 8; ++i) accS[i] = (f32x4){0.f,0.f,0.f,0.f};
    #pragma unroll
    for (int ks = 0; ks < 2; ++ks) {
        const int ch = ks*4 + q;
        const s16x8 af = ks ? qf1 : qf0;
        #pragma unroll
        for (int vt = 0; vt < 8; ++vt) {
            const int br = (vt << 4) + l15;
            s16x8 bf = *(const s16x8*)(ldsK + br*128 + ((ch ^ (br & 7)) << 4));
            accS[vt] = MFMA_BF16(af, bf, accS[vt], 0, 0, 0);
        }
    }
    __syncthreads();                         // K dead -> P region writable

    // ---- stats, P (wave-local), merged scales (l15==0 lanes, wave-local)
    #pragma unroll
    for (int r = 0; r < 4; ++r) {
        const int ww = (wid << 4) + (q << 2) + r;
        float m = -3.0e38f;
        #pragma unroll
        for (int vt = 0; vt < 8; ++vt) m = fmaxf(m, accS[vt][r]);
        m = fmaxf(m, __shfl_xor(m, 1)); m = fmaxf(m, __shfl_xor(m, 2));
        m = fmaxf(m, __shfl_xor(m, 4)); m = fmaxf(m, __shfl_xor(m, 8));
        float s = 0.f;
        #pragma unroll
        for (int vt = 0; vt < 8; ++vt) {
            const float e = __expf(accS[vt][r] - m);
            s += e;
            const int v = (vt << 4) + l15;
            *(u16*)(ldsP + ww*256 + (((v >> 3) ^ (ww & 7)) << 4) + (v & 7)*2)
                = f2b(e);
        }
        s += __shfl_xor(s, 1); s += __shfl_xor(s, 2);
        s += __shfl_xor(s, 4); s += __shfl_xor(s, 8);
        if (l15 == 0) {                      // merge with column stats
            const float mh  = Mh[(b*W_ + ww)*H_ + h];
            const float shv = Sh[(b*W_ + ww)*H_ + h];
            const float M = fmaxf(mh, m);
            const float S = shv*__expf(mh - M) + s*__expf(m - M);
            sScw[ww] = __expf(m - M) / S;
            sSch[ww] = __expf(mh - M) / S;
        }
    }
    // (no barrier: P + scales wave-local; V0 ready since first barrier)
    float scw[4], sch[4];
    #pragma unroll
    for (int r = 0; r < 4; ++r) { scw[r] = sScw[wbase + r]; sch[r] = sSch[wbase + r]; }

    // ---- V chunk1 into regs NOW (latency hides under PV0 MFMAs)
    s16x8 vh[2];
    #pragma unroll
    for (int i = 0; i < 2; ++i) {
        const int idx = i*512 + t;
        const int c = 64 + (idx >> 4), o = idx & 15;
        vh[i] = *(const s16x8*)(const void*)
                (Vn + (size_t)(b*C_ + c)*HW_ + h*W_ + o*8);
    }

    const u16* o2p = O2 + (size_t)(b*H_ + h)*W_*C_;

#define KR_PV(accv) do {                                                  \
    _Pragma("unroll")                                                     \
    for (int ks = 0; ks < 4; ++ks) {                                      \
        const int ch = ks*4 + q;                                          \
        s16x8 afp = *(const s16x8*)(ldsP + arow*256 + ((ch ^ (arow & 7)) << 4)); \
        _Pragma("unroll")                                                 \
        for (int ct = 0; ct < 4; ++ct) {                                  \
            const int vr = (ct << 4) + l15;                               \
            s16x8 bfv = *(const s16x8*)(ldsV + vr*256 + ((ch ^ (vr & 7)) << 4)); \
            accv[ct] = MFMA_BF16(afp, bfv, accv[ct], 0, 0, 0);            \
        }                                                                 \
    } } while(0)
// direct-read epilogue (no persistent prefetch arrays: VGPR discipline)
#define KR_EPI(k, accv) do {                                              \
    _Pragma("unroll")                                                     \
    for (int ct = 0; ct < 4; ++ct) {                                      \
        const int c = (k)*64 + (ct << 4) + l15;                           \
        const size_t ga = (size_t)(b*C_ + c)*HW_ + h*W_ + wbase;          \
        const f32x4 xv = *(const f32x4*)(const void*)(x + ga);            \
        f32x4 res;                                                        \
        _Pragma("unroll")                                                 \
        for (int r = 0; r < 4; ++r) {                                     \
            const float o2 = b2f(o2p[(size_t)(wbase + r)*C_ + c]);        \
            res[r] = gam*(accv[ct][r]*scw[r] + o2*sch[r]) + xv[r];        \
        }                                                                 \
        *(f32x4*)(void*)(out + ga) = res;                                 \
    } } while(0)

    f32x4 accO[4];
    #pragma unroll
    for (int i = 0; i < 4; ++i) accO[i] = (f32x4){0.f,0.f,0.f,0.f};
    KR_PV(accO);                             // chunk0 (c 0..63)
    __syncthreads();                         // V0 reads done
    #pragma unroll
    for (int i = 0; i < 2; ++i) {            // dsw V1; reload vh <- V2
        const int idx = i*512 + t;
        const int lc = idx >> 4, o = idx & 15;
        *(s16x8*)(ldsV + lc*256 + ((o ^ (lc & 7)) << 4)) = vh[i];
    }
    #pragma unroll
    for (int i = 0; i < 2; ++i) {
        const int idx = i*512 + t;
        const int c = 128 + (idx >> 4), o = idx & 15;
        vh[i] = *(const s16x8*)(const void*)
                (Vn + (size_t)(b*C_ + c)*HW_ + h*W_ + o*8);
    }
    KR_EPI(0, accO);                         // stores cover dsw drain
    __syncthreads();                         // V1 visible
    #pragma unroll
    for (int i = 0; i < 4; ++i) accO[i] = (f32x4){0.f,0.f,0.f,0.f};
    KR_PV(accO);                             // chunk1 (c 64..127)
    __syncthreads();                         // V1 reads done
    #pragma unroll
    for (int i = 0; i < 2; ++i) {            // dsw V2
        const int idx = i*512 + t;
        const int lc = idx >> 4, o = idx & 15;
        *(s16x8*)(ldsV + lc*256 + ((o ^ (lc & 7)) << 4)) = vh[i];
    }
    KR_EPI(1, accO);
    __syncthreads();                         // V2 visible
    #pragma unroll
    for (int i = 0; i < 4; ++i) accO[i] = (f32x4){0.f,0.f,0.f,0.f};
    KR_PV(accO);                             // chunk2 (c 128..191)
    KR_EPI(2, accO);
#undef KR_PV
#undef KR_EPI
}

extern "C" void kernel_launch(void* const* d_in, const int* in_sizes, int n_in,
                              void* d_out, int out_size, void* d_ws, size_t ws_size,
                              hipStream_t stream)
{
    const float* x  = (const float*)d_in[0];
    const float* Wq = (const float*)d_in[1];
    const float* bq = (const float*)d_in[2];
    const float* Wk = (const float*)d_in[3];
    const float* bk = (const float*)d_in[4];
    const float* Wv = (const float*)d_in[5];
    const float* bv = (const float*)d_in[6];
    const float* gm = (const float*)d_in[7];
    float* out = (float*)d_out;

    u16* Qc = (u16*)d_ws;
    u16* Kc = Qc + 8388608;
    u16* Vn = Kc + 8388608;
    u16* Vc = Vn + 25165824;
    u16* O2 = Vc + 25165824;                 // 25165824 u16
    float* Mh = (float*)(O2 + 25165824);
    float* Sh = Mh + 131072;
    u16*  Wb = (u16*)(Sh + 131072);          // 61440 u16
    float* Bb = (float*)(Wb + 61440);        // 320 f32

    hipLaunchKernelGGL(kwcast, dim3(320), dim3(256), 0, stream,
                       Wq, bq, Wk, bk, Wv, bv, Wb, Bb);
    hipLaunchKernelGGL(kprojM, dim3(H_, B_), dim3(256), 0, stream,
                       x, Wb, Bb, Qc, Kc, Vn);
    hipLaunchKernelGGL(ktrv, dim3(C_, B_), dim3(256), 0, stream, Vn, Vc);
    hipLaunchKernelGGL(kC, dim3(W_, B_), dim3(512), 49152, stream,
                       Qc, Kc, Vc, O2, Mh, Sh);
    hipLaunchKernelGGL(kR, dim3(H_, B_), dim3(512), 50176, stream,
                       Qc, Kc, Vn, O2, Mh, Sh, x, gm, out);
}